// Round 6
// baseline (873.172 us; speedup 1.0000x reference)
//
#include <hip/hip_runtime.h>
#include <stdint.h>

typedef uint16_t u16;
typedef __bf16 bf16x8 __attribute__((ext_vector_type(8)));
typedef float f32x4 __attribute__((ext_vector_type(4)));

#define DEV static __device__ __forceinline__

DEV float bfbits_lo(uint32_t w) { union { uint32_t i; float f; } v; v.i = w << 16; return v.f; }
DEV float bfbits_hi(uint32_t w) { union { uint32_t i; float f; } v; v.i = w & 0xffff0000u; return v.f; }
DEV u16 f2bf(float f) {
    union { float f; uint32_t i; } v; v.f = f;
    uint32_t x = v.i;
    uint32_t r = (x + 0x7fffu + ((x >> 16) & 1u)) >> 16;  // RNE
    return (u16)r;
}

// DPP cross-lane permute within each 16-lane row: returns permuted value.
// CTRL: 0x124=row_ror:4, 0x128=row_ror:8, 0xB1=quad_perm xor1, 0x4E=quad_perm xor2
template <int CTRL>
DEV float dpp_get(float x) {
    union { float f; int i; } a, r;
    a.f = x;
    r.i = __builtin_amdgcn_update_dpp(0, a.i, CTRL, 0xf, 0xf, false);
    return r.f;
}

// async global->LDS DMA, 16B per lane. LDS dest must be wave-uniform base +
// lane*16 (HW semantics); our staging slots (base + tid*16) satisfy this.
#define GLL16(g, l)                                                        \
    __builtin_amdgcn_global_load_lds(                                      \
        (const __attribute__((address_space(1))) uint32_t*)(g),            \
        (__attribute__((address_space(3))) uint32_t*)(l), 16, 0, 0)

// Packed operand layout ("panels"): element (row, k) of a [R x K] matrix
// lives at u16 index ((k>>3)*R + row)*8 + (k&7)  == uint4 slot (k>>3)*R + row.
// A wave staging 64 consecutive rows of one panel reads 1KB CONTIGUOUS.

// ------------------------------------------------------------- PREP ----
// blocks 0..4095: weight transpose+pack; 4096..8191: F pack; 8192..8203:
// bias concat; 8204..12299: KNN.
__global__ __launch_bounds__(256) void prep_kernel(
    const float* __restrict__ verts, const float* __restrict__ F,
    const float* __restrict__ Wq, const float* __restrict__ Wk,
    const float* __restrict__ Wv, const float* __restrict__ Wo,
    const float* __restrict__ W1, const float* __restrict__ W2,
    const float* __restrict__ bq, const float* __restrict__ bk,
    const float* __restrict__ bv,
    u16* __restrict__ WqkvT, u16* __restrict__ WoT,
    u16* __restrict__ W1T, u16* __restrict__ W2T,
    float* __restrict__ bqkv, u16* __restrict__ Fb, int* __restrict__ nbr) {
    int blk = blockIdx.x;
    int tid = threadIdx.x;
    if (blk < 4096) {
        // transpose W[K][Nsrc] -> packed BT panels [(k>>3)*NB + noff + n][k&7]
        const float* in; u16* outp; int K, Nsrc, NB, noff, t = blk;
        if (t < 512) { in = Wq; outp = WqkvT; K = 512; Nsrc = 1024; NB = 3072; noff = 0; }
        else if (t < 1024) { t -= 512; in = Wk; outp = WqkvT; K = 512; Nsrc = 1024; NB = 3072; noff = 1024; }
        else if (t < 1536) { t -= 1024; in = Wv; outp = WqkvT; K = 512; Nsrc = 1024; NB = 3072; noff = 2048; }
        else if (t < 2048) { t -= 1536; in = Wo; outp = WoT; K = 1024; Nsrc = 512; NB = 512; noff = 0; }
        else if (t < 3072) { t -= 2048; in = W1; outp = W1T; K = 512; Nsrc = 2048; NB = 2048; noff = 0; }
        else { t -= 3072; in = W2; outp = W2T; K = 2048; Nsrc = 512; NB = 512; noff = 0; }
        int tilesX = Nsrc >> 5;
        int bx = t % tilesX, by = t / tilesX;
        int x0 = bx * 32, y0 = by * 32;
        __shared__ float tile[32][33];
        int tx = tid & 31, ty = tid >> 5;  // 32 x 8
#pragma unroll
        for (int r = 0; r < 4; r++) {
            int y = y0 + ty + r * 8;       // k index
            tile[ty + r * 8][tx] = in[(size_t)y * Nsrc + x0 + tx];
        }
        __syncthreads();
#pragma unroll
        for (int r = 0; r < 4; r++) {
            int n = x0 + ty + r * 8;       // source col
            int k = y0 + tx;
            outp[(((size_t)(k >> 3) * NB + noff + n) << 3) + (k & 7)] = f2bf(tile[tx][ty + r * 8]);
        }
    } else if (blk < 8192) {
        // pack F[16384][512] -> Fb panels (reads contiguous, writes strided->L2)
        int gi = (blk - 4096) * 256 + tid;   // 16384*64 slots
        int row = gi >> 6, p = gi & 63;
        const float4* src = (const float4*)(F + (size_t)row * 512 + p * 8);
        float4 a = src[0], c = src[1];
        uint32_t w0 = f2bf(a.x) | ((uint32_t)f2bf(a.y) << 16);
        uint32_t w1 = f2bf(a.z) | ((uint32_t)f2bf(a.w) << 16);
        uint32_t w2 = f2bf(c.x) | ((uint32_t)f2bf(c.y) << 16);
        uint32_t w3 = f2bf(c.z) | ((uint32_t)f2bf(c.w) << 16);
        ((uint4*)Fb)[(size_t)p * 16384 + row] = make_uint4(w0, w1, w2, w3);
    } else if (blk < 8204) {
        int i = (blk - 8192) * 256 + tid;
        if (i < 1024) bqkv[i] = bq[i];
        else if (i < 2048) bqkv[i] = bk[i - 1024];
        else if (i < 3072) bqkv[i] = bv[i - 2048];
    } else {
        // ---- KNN top-20 (1 wave per query), packed-argmin (R3, verified) ----
        int wv = (blk - 8204) * 4 + (tid >> 6);
        int l = tid & 63;
        int b = wv >> 10, n = wv & 1023;
        const float* vb = verts + (size_t)b * 1024 * 3;
        float qx = vb[n * 3 + 0], qy = vb[n * 3 + 1], qz = vb[n * 3 + 2];
        float q2 = qx * qx + qy * qy + qz * qz;
        float pd[16];
#pragma unroll
        for (int t = 0; t < 16; t++) {
            int p = l + 64 * t;
            float px = vb[p * 3 + 0], py = vb[p * 3 + 1], pz = vb[p * 3 + 2];
            float p2 = px * px + py * py + pz * pz;
            float dot = qx * px + qy * py + qz * pz;
            float dv = q2 + p2 - 2.f * dot + 1.0f;
            uint32_t bits = (__float_as_uint(dv) & ~0xFu) | (uint32_t)t;
            pd[t] = __uint_as_float(bits);
        }
        int* outp = nbr + (size_t)wv * 20;
        for (int it = 0; it < 20; it++) {
            float m01 = fminf(pd[0], pd[1]),   m23 = fminf(pd[2], pd[3]);
            float m45 = fminf(pd[4], pd[5]),   m67 = fminf(pd[6], pd[7]);
            float m89 = fminf(pd[8], pd[9]),   mab = fminf(pd[10], pd[11]);
            float mcd = fminf(pd[12], pd[13]), mef = fminf(pd[14], pd[15]);
            float m = fminf(fminf(fminf(m01, m23), fminf(m45, m67)),
                            fminf(fminf(m89, mab), fminf(mcd, mef)));
            m = fminf(m, dpp_get<0x124>(m));
            m = fminf(m, dpp_get<0x128>(m));
            m = fminf(m, dpp_get<0xB1>(m));
            m = fminf(m, dpp_get<0x4E>(m));
            m = fminf(m, __shfl_xor(m, 16));
            m = fminf(m, __shfl_xor(m, 32));
            bool mine = false;
#pragma unroll
            for (int t = 0; t < 16; t++) mine |= (pd[t] == m);
            unsigned long long bal = __ballot(mine);
            int wl = (int)__builtin_ctzll(bal);
            if (l == wl) {
#pragma unroll
                for (int t = 0; t < 16; t++) if (pd[t] == m) pd[t] = 3.4e38f;
            }
            if (l == 0) outp[it] = ((int)(__float_as_uint(m) & 15u)) * 64 + wl;
        }
    }
}

// ---------------------------------------------------------------- GEMM ----
// C[M,N] = A[M,K] * B[K,N], both operands packed-panel. bf16 in, fp32 accum,
// MFMA 16x16x32, BK=32, 128x128 tile. Staging via global_load_lds DMA
// (16B/lane); counted vmcnt(4) 2-phase schedule (R4, verified correct;
// perf-neutral vs register ping-pong -> barrier structure is the cap, not
// staging).
// EPI: 0 bias->bf16 row-major | 1 bias+relu->PACKED bf16 | 3 partial->fp32
template <int EPI>
__global__ __launch_bounds__(256) void gemm_bt(const u16* __restrict__ A,
                                               const u16* __restrict__ BT,
                                               const float* __restrict__ bias,
                                               u16* __restrict__ Cb,
                                               float* __restrict__ Cf,
                                               float* __restrict__ Cf2,
                                               int M, int N, int Klen,
                                               int MA, int NB, int Koff) {
    __shared__ __align__(16) u16 As0[4096], As1[4096];   // 8KB each: [kq][row][8]
    __shared__ __align__(16) u16 Bs0[4096], Bs1[4096];
    int tid = threadIdx.x;
    int id = blockIdx.y * gridDim.x + blockIdx.x;
    int by = id % gridDim.y, bx = id / gridDim.y;
    int m0 = by * 128, n0 = bx * 128;
    int kz = blockIdx.z;
    const uint4* A4 = (const uint4*)A + (size_t)kz * (Koff >> 3) * MA;
    const uint4* B4 = (const uint4*)BT + (size_t)kz * (Koff >> 3) * NB;
    int w = tid >> 6, l = tid & 63;
    int wr = w >> 1, wc = w & 1, quad = l >> 4, ln = l & 15;
    // staging: slot i=tid -> (panel q=tid>>7, row tid&127); i=tid+256 -> q+2
    int qA = tid >> 7, rA = tid & 127;
    const uint4* pA0 = A4 + (size_t)qA * MA + m0 + rA;
    const uint4* pA1 = pA0 + 2 * (size_t)MA;
    const uint4* pB0 = B4 + (size_t)qA * NB + n0 + rA;
    const uint4* pB1 = pB0 + 2 * (size_t)NB;

    f32x4 acc[4][4];
#pragma unroll
    for (int i = 0; i < 4; i++)
#pragma unroll
        for (int j = 0; j < 4; j++) acc[i][j] = (f32x4){0.f, 0.f, 0.f, 0.f};

#define STAGE(As, Bs, ko) do { size_t kq = (size_t)((ko) >> 3);              \
        GLL16(pA0 + kq * MA, (char*)(As) + tid * 16);                        \
        GLL16(pA1 + kq * MA, (char*)(As) + (tid + 256) * 16);                \
        GLL16(pB0 + kq * NB, (char*)(Bs) + tid * 16);                        \
        GLL16(pB1 + kq * NB, (char*)(Bs) + (tid + 256) * 16); } while (0)
#define COMPUTE(Asb, Bsb) do {                                                            \
        const bf16x8* Av = (const bf16x8*)(Asb);                                          \
        const bf16x8* Bv = (const bf16x8*)(Bsb);                                          \
        bf16x8 af[4], bfr[4];                                                             \
        _Pragma("unroll")                                                                 \
        for (int i = 0; i < 4; i++) af[i] = Av[quad * 128 + wr * 64 + i * 16 + ln];       \
        _Pragma("unroll")                                                                 \
        for (int j = 0; j < 4; j++) bfr[j] = Bv[quad * 128 + wc * 64 + j * 16 + ln];      \
        _Pragma("unroll")                                                                 \
        for (int i = 0; i < 4; i++)                                                       \
            _Pragma("unroll")                                                             \
            for (int j = 0; j < 4; j++)                                                   \
                acc[i][j] = __builtin_amdgcn_mfma_f32_16x16x32_bf16(af[i], bfr[j], acc[i][j], 0, 0, 0); \
    } while (0)

    int nIter = Klen >> 5;   // even, >= 4 for all shapes used
    STAGE(As0, Bs0, 0);                                   // 4 loads in flight
    for (int kt = 0; kt < nIter; kt += 2) {
        STAGE(As1, Bs1, (kt + 1) * 32);                   // +4 -> 8 in flight
        asm volatile("s_waitcnt vmcnt(4)" ::: "memory");  // tile kt landed
        __builtin_amdgcn_s_barrier();
        COMPUTE(As0, Bs0);                                // tile kt
        __builtin_amdgcn_s_barrier();                     // reads of As0/Bs0 done
        if (kt + 2 < nIter) {
            STAGE(As0, Bs0, (kt + 2) * 32);               // +4 -> 8 in flight
            asm volatile("s_waitcnt vmcnt(4)" ::: "memory");  // tile kt+1 landed
        } else {
            asm volatile("s_waitcnt vmcnt(0)" ::: "memory");
        }
        __builtin_amdgcn_s_barrier();
        COMPUTE(As1, Bs1);                                // tile kt+1
        __builtin_amdgcn_s_barrier();                     // reads of As1/Bs1 done
    }
#undef STAGE
#undef COMPUTE

    float* Cfz = (EPI == 3) ? (kz ? Cf2 : Cf) : Cf;
    // epilogue: row = m0+wr*64+i*16+quad*4+r, col = n0+wc*64+j*16+ln
#pragma unroll
    for (int i = 0; i < 4; i++) {
        int row_base = m0 + wr * 64 + i * 16 + quad * 4;
#pragma unroll
        for (int j = 0; j < 4; j++) {
            int col = n0 + wc * 64 + j * 16 + ln;
            float bb = (EPI == 3) ? 0.f : bias[col];
#pragma unroll
            for (int r = 0; r < 4; r++) {
                int row = row_base + r;
                float v = acc[i][j][r] + bb;
                if (EPI == 0) Cb[(size_t)row * N + col] = f2bf(v);
                else if (EPI == 1)  // packed output (next GEMM's A operand)
                    Cb[(((size_t)(col >> 3) * M + row) << 3) + (col & 7)] = f2bf(v > 0.f ? v : 0.f);
                else Cfz[(size_t)row * N + col] = v;
            }
        }
    }
}

// ----------------------------------------------------- sparse attention ----
// R5 change: logits wj[20] move from VGPRs to LDS (1.25KB/block), and
// __launch_bounds__(256, 8) pins the allocator to the <=64-VGPR tier ->
// 8 waves/SIMD cap (was 92 VGPR -> <=128 tier -> 4 waves/SIMD). Mechanism:
// kernel is latency-bound (VALUBusy 49%, HBM 20%) -> resident waves are the
// lever. Loop bodies are byte-identical to the proven structure (R1/R2:
// perturbing the load/dot/shfl chain balloons registers); the only body
// change is the logit sink: lane sx==0 ds_writes the group's logit, phase 2
// broadcast-reads it back and re-runs the cheap TRANS-pipe exp. Wave-internal
// LDS ordering needs no barrier.
// XCD swizzle proven: FETCH 305MB -> ~111MB. DO NOT TOUCH THE LOOP BODY.
__global__ __launch_bounds__(256, 8) void attn_kernel(const u16* __restrict__ QKV,
                                                      const int* __restrict__ nbr,
                                                      u16* __restrict__ outA) {
    __shared__ float wjs[4][4][20];   // [wave][head][j] raw logits
    int tid = threadIdx.x;
    int bid = blockIdx.x;
    int swz = (bid & 7) * 512 + (bid >> 3);   // 4096 blocks, bijective
    int wq = tid >> 6;
    int wv = swz * 4 + wq;  // b*1024+n
    int l = tid & 63;
    int h = l >> 4, sx = l & 15;
    int bbase = (wv >> 10) << 10;

    int nv = 0;
    if (l < 20) nv = nbr[(size_t)wv * 20 + l];

    const uint32_t* qp = (const uint32_t*)(QKV + (size_t)wv * 3072 + h * 256 + sx * 16);
    uint32_t qw[8];
    *(uint4*)(qw) = *(const uint4*)qp;
    *(uint4*)(qw + 4) = *(const uint4*)(qp + 4);
    float qf[16];
#pragma unroll
    for (int i = 0; i < 8; i++) { qf[2 * i] = bfbits_lo(qw[i]); qf[2 * i + 1] = bfbits_hi(qw[i]); }

    float* wrow = &wjs[wq][h][0];
#pragma unroll
    for (int j = 0; j < 20; j++) {
        int m = __shfl(nv, j);
        const uint32_t* kp = (const uint32_t*)(QKV + (size_t)(bbase + m) * 3072 + 1024 + h * 256 + sx * 16);
        uint32_t kw[8];
        *(uint4*)(kw) = *(const uint4*)kp;
        *(uint4*)(kw + 4) = *(const uint4*)(kp + 4);
        float acc = 0.f;
#pragma unroll
        for (int i = 0; i < 8; i++) {
            acc += qf[2 * i] * bfbits_lo(kw[i]);
            acc += qf[2 * i + 1] * bfbits_hi(kw[i]);
        }
#pragma unroll
        for (int off = 1; off < 16; off <<= 1) acc += __shfl_xor(acc, off);
        if (sx == 0) wrow[j] = acc * 0.0625f;
    }
    float ssum = 0.f;
#pragma unroll
    for (int j = 0; j < 20; j++) ssum += __expf(wrow[j]);
    float inv = 1.f / ssum;

    float o[16];
#pragma unroll
    for (int i = 0; i < 16; i++) o[i] = 0.f;
#pragma unroll
    for (int j = 0; j < 20; j++) {
        int m = __shfl(nv, j);
        const uint32_t* vp = (const uint32_t*)(QKV + (size_t)(bbase + m) * 3072 + 2048 + h * 256 + sx * 16);
        uint32_t vw[8];
        *(uint4*)(vw) = *(const uint4*)vp;
        *(uint4*)(vw + 4) = *(const uint4*)(vp + 4);
        float ww = __expf(wrow[j]) * inv;
#pragma unroll
        for (int i = 0; i < 8; i++) {
            o[2 * i] += ww * bfbits_lo(vw[i]);
            o[2 * i + 1] += ww * bfbits_hi(vw[i]);
        }
    }
    uint32_t ow[8];
#pragma unroll
    for (int i = 0; i < 8; i++) ow[i] = f2bf(o[2 * i]) | ((uint32_t)f2bf(o[2 * i + 1]) << 16);
    // packed store: cols h*256+sx*16 .. +15 -> panels h*32+sx*2, h*32+sx*2+1, row wv
    size_t slot = (size_t)(h * 32 + sx * 2) * 16384 + wv;
    ((uint4*)outA)[slot] = make_uint4(ow[0], ow[1], ow[2], ow[3]);
    ((uint4*)outA)[slot + 16384] = make_uint4(ow[4], ow[5], ow[6], ow[7]);
}

// ------------------------------------------------- LN over split-K sum ----
// LN(P0 + P1 + res + biasv) -> Yf fp32 (+ Yb PACKED bf16 if WB)
template <int WB>
__global__ __launch_bounds__(256) void ln12p_kernel(const float* __restrict__ P0,
                                                    const float* __restrict__ P1,
                                                    const float* __restrict__ res,
                                                    const float* __restrict__ biasv,
                                                    const float* __restrict__ g,
                                                    const float* __restrict__ bparm,
                                                    float* __restrict__ Yf,
                                                    u16* __restrict__ Yb) {
    int tid = threadIdx.x;
    int row = blockIdx.x * 4 + (tid >> 6);
    int l = tid & 63;
    size_t base = (size_t)row * 512;
    const float4* p0 = (const float4*)(P0 + base) + l * 2;
    const float4* p1 = (const float4*)(P1 + base) + l * 2;
    const float4* rr = (const float4*)(res + base) + l * 2;
    const float4* bv = (const float4*)biasv + l * 2;
    float xs[8];
#pragma unroll
    for (int h = 0; h < 2; h++) {
        float4 a = p0[h], b = p1[h], c = rr[h], d = bv[h];
        xs[4 * h + 0] = a.x + b.x + c.x + d.x;
        xs[4 * h + 1] = a.y + b.y + c.y + d.y;
        xs[4 * h + 2] = a.z + b.z + c.z + d.z;
        xs[4 * h + 3] = a.w + b.w + c.w + d.w;
    }
    float s = 0.f;
#pragma unroll
    for (int i = 0; i < 8; i++) s += xs[i];
#pragma unroll
    for (int off = 32; off >= 1; off >>= 1) s += __shfl_xor(s, off);
    float mu = s * (1.f / 512.f);
    float q = 0.f;
#pragma unroll
    for (int i = 0; i < 8; i++) { float dd = xs[i] - mu; q += dd * dd; }
#pragma unroll
    for (int off = 32; off >= 1; off >>= 1) q += __shfl_xor(q, off);
    float var = q * (1.f / 512.f);
    float rs = rsqrtf(var + 1e-5f);
    const float4* gp = (const float4*)g + l * 2;
    const float4* bp = (const float4*)bparm + l * 2;
    float4 g0 = gp[0], g1 = gp[1], b0 = bp[0], b1 = bp[1];
    float gg[8] = {g0.x, g0.y, g0.z, g0.w, g1.x, g1.y, g1.z, g1.w};
    float bbv[8] = {b0.x, b0.y, b0.z, b0.w, b1.x, b1.y, b1.z, b1.w};
    float y[8];
#pragma unroll
    for (int i = 0; i < 8; i++) y[i] = (xs[i] - mu) * rs * gg[i] + bbv[i];
    float4* yo = (float4*)(Yf + base) + l * 2;
    yo[0] = make_float4(y[0], y[1], y[2], y[3]);
    yo[1] = make_float4(y[4], y[5], y[6], y[7]);
    if (WB) {
        uint32_t w0 = f2bf(y[0]) | ((uint32_t)f2bf(y[1]) << 16);
        uint32_t w1 = f2bf(y[2]) | ((uint32_t)f2bf(y[3]) << 16);
        uint32_t w2 = f2bf(y[4]) | ((uint32_t)f2bf(y[5]) << 16);
        uint32_t w3 = f2bf(y[6]) | ((uint32_t)f2bf(y[7]) << 16);
        // packed: lane l holds k = l*8..l*8+7 of this row -> panel l
        ((uint4*)Yb)[(size_t)l * 16384 + row] = make_uint4(w0, w1, w2, w3);
    }
}

// ------------------------------------------------------------ launcher ----
extern "C" void kernel_launch(void* const* d_in, const int* in_sizes, int n_in,
                              void* d_out, int out_size, void* d_ws, size_t ws_size,
                              hipStream_t stream) {
    const float* verts = (const float*)d_in[0];
    const float* F = (const float*)d_in[1];
    const float* Wq = (const float*)d_in[2];
    const float* bq = (const float*)d_in[3];
    const float* Wk = (const float*)d_in[4];
    const float* bk = (const float*)d_in[5];
    const float* Wv = (const float*)d_in[6];
    const float* bv = (const float*)d_in[7];
    const float* Wo = (const float*)d_in[8];
    const float* bo = (const float*)d_in[9];
    const float* ln1g = (const float*)d_in[10];
    const float* ln1b = (const float*)d_in[11];
    const float* W1 = (const float*)d_in[12];
    const float* b1 = (const float*)d_in[13];
    const float* W2 = (const float*)d_in[14];
    const float* b2 = (const float*)d_in[15];
    const float* ln2g = (const float*)d_in[16];
    const float* ln2b = (const float*)d_in[17];
    float* out = (float*)d_out;

    char* ws = (char*)d_ws;
    // arena (lifetime-overlapped), ~177.5 MB:
    u16* QKV = (u16*)(ws);                         // [0, 96MB)  G1 -> attn (row-major)
    float* Q0 = (float*)(ws);                      // [0, 32MB)  G2 partial 0 -> LN1
    float* Q1 = (float*)(ws + 33554432);           // [32, 64MB) G2 partial 1 -> LN1
    u16* Hb = (u16*)(ws);                          // [0, 64MB)  G3 -> G4 (packed)
    float* P1 = (float*)(ws + 67108864);           // [64, 96MB) G4 partial 1 -> LN2
    u16* ATT = (u16*)(ws + 100663296);             // [96, 128MB) attn -> G2 (packed)
    u16* xb = ATT;                                 //   reuse: LN1 -> G3 (packed)
    float* P0 = (float*)(ws + 100663296);          //   reuse: G4 partial 0 -> LN2
    u16* Fb = (u16*)(ws + 134217728);              // [128, 144.8MB) prep -> G1 (packed)
    float* X32 = (float*)(ws + 134217728);         //   reuse: LN1 -> LN2 (33.5MB)
    char* wsw = ws + 167772160;
    u16* WqkvT = (u16*)(wsw);                      // 3,145,728 (packed)
    u16* WoT = (u16*)(wsw + 3145728);              // 1,048,576 (packed)
    u16* W1T = (u16*)(wsw + 4194304);              // 2,097,152 (packed)
    u16* W2T = (u16*)(wsw + 6291456);              // 2,097,152 (packed)
    float* bqkv = (float*)(wsw + 8388608);         // 16,384 (padded)
    int* nbr = (int*)(wsw + 8404992);              // 1,310,720

    // PREP (one dispatch): transposes+pack + F pack + bias + KNN
    prep_kernel<<<12300, 256, 0, stream>>>(verts, F, Wq, Wk, Wv, Wo, W1, W2,
                                           bq, bk, bv, WqkvT, WoT, W1T, W2T,
                                           bqkv, Fb, nbr);
    // G1: QKV = Fb @ Wqkv + bias -> bf16 row-major [16384, 3072]
    gemm_bt<0><<<dim3(24, 128, 1), 256, 0, stream>>>(Fb, WqkvT, bqkv, QKV, nullptr, nullptr,
                                                     16384, 3072, 512, 16384, 3072, 0);
    // sparse attention -> ATT packed [16384, 1024]
    attn_kernel<<<4096, 256, 0, stream>>>(QKV, nbr, ATT);
    // G2 split-K x2: Q0/Q1 = ATT @ Wo (partials) [16384, 512]
    gemm_bt<3><<<dim3(4, 128, 2), 256, 0, stream>>>(ATT, WoT, nullptr, nullptr, Q0, Q1,
                                                    16384, 512, 512, 16384, 512, 512);
    // LN1: LN(Q0+Q1+bo+F) -> X32 fp32 + xb packed bf16
    ln12p_kernel<1><<<4096, 256, 0, stream>>>(Q0, Q1, F, bo, ln1g, ln1b, X32, xb);
    // G3: Hb = relu(xb @ W1 + b1) -> packed bf16 [16384, 2048]
    gemm_bt<1><<<dim3(16, 128, 1), 256, 0, stream>>>(xb, W1T, b1, Hb, nullptr, nullptr,
                                                     16384, 2048, 512, 16384, 2048, 0);
    // G4 split-K x2: P0/P1 = Hb @ W2 (partials) [16384, 512]
    gemm_bt<3><<<dim3(4, 128, 2), 256, 0, stream>>>(Hb, W2T, nullptr, nullptr, P0, P1,
                                                    16384, 512, 1024, 16384, 512, 1024);
    // LN2: LN(P0+P1+b2+X32) -> out
    ln12p_kernel<0><<<4096, 256, 0, stream>>>(P0, P1, X32, b2, ln2g, ln2b, out, nullptr);
}

// Round 7
// 534.745 us; speedup vs baseline: 1.6329x; 1.6329x over previous
//
#include <hip/hip_runtime.h>
#include <stdint.h>

typedef uint16_t u16;
typedef __bf16 bf16x8 __attribute__((ext_vector_type(8)));
typedef float f32x4 __attribute__((ext_vector_type(4)));

#define DEV static __device__ __forceinline__

DEV float bfbits_lo(uint32_t w) { union { uint32_t i; float f; } v; v.i = w << 16; return v.f; }
DEV float bfbits_hi(uint32_t w) { union { uint32_t i; float f; } v; v.i = w & 0xffff0000u; return v.f; }
DEV u16 f2bf(float f) {
    union { float f; uint32_t i; } v; v.f = f;
    uint32_t x = v.i;
    uint32_t r = (x + 0x7fffu + ((x >> 16) & 1u)) >> 16;  // RNE
    return (u16)r;
}

// DPP cross-lane permute within each 16-lane row: returns permuted value.
// CTRL: 0x124=row_ror:4, 0x128=row_ror:8, 0xB1=quad_perm xor1, 0x4E=quad_perm xor2
template <int CTRL>
DEV float dpp_get(float x) {
    union { float f; int i; } a, r;
    a.f = x;
    r.i = __builtin_amdgcn_update_dpp(0, a.i, CTRL, 0xf, 0xf, false);
    return r.f;
}

// async global->LDS DMA, 16B per lane. LDS dest must be wave-uniform base +
// lane*16 (HW semantics); our staging slots (base + tid*16) satisfy this.
#define GLL16(g, l)                                                        \
    __builtin_amdgcn_global_load_lds(                                      \
        (const __attribute__((address_space(1))) uint32_t*)(g),            \
        (__attribute__((address_space(3))) uint32_t*)(l), 16, 0, 0)

// Packed operand layout ("panels"): element (row, k) of a [R x K] matrix
// lives at u16 index ((k>>3)*R + row)*8 + (k&7)  == uint4 slot (k>>3)*R + row.
// A wave staging 64 consecutive rows of one panel reads 1KB CONTIGUOUS.

// ------------------------------------------------------------- PREP ----
// blocks 0..4095: weight transpose+pack; 4096..8191: F pack; 8192..8203:
// bias concat; 8204..12299: KNN.
__global__ __launch_bounds__(256) void prep_kernel(
    const float* __restrict__ verts, const float* __restrict__ F,
    const float* __restrict__ Wq, const float* __restrict__ Wk,
    const float* __restrict__ Wv, const float* __restrict__ Wo,
    const float* __restrict__ W1, const float* __restrict__ W2,
    const float* __restrict__ bq, const float* __restrict__ bk,
    const float* __restrict__ bv,
    u16* __restrict__ WqkvT, u16* __restrict__ WoT,
    u16* __restrict__ W1T, u16* __restrict__ W2T,
    float* __restrict__ bqkv, u16* __restrict__ Fb, int* __restrict__ nbr) {
    int blk = blockIdx.x;
    int tid = threadIdx.x;
    if (blk < 4096) {
        // transpose W[K][Nsrc] -> packed BT panels [(k>>3)*NB + noff + n][k&7]
        const float* in; u16* outp; int K, Nsrc, NB, noff, t = blk;
        if (t < 512) { in = Wq; outp = WqkvT; K = 512; Nsrc = 1024; NB = 3072; noff = 0; }
        else if (t < 1024) { t -= 512; in = Wk; outp = WqkvT; K = 512; Nsrc = 1024; NB = 3072; noff = 1024; }
        else if (t < 1536) { t -= 1024; in = Wv; outp = WqkvT; K = 512; Nsrc = 1024; NB = 3072; noff = 2048; }
        else if (t < 2048) { t -= 1536; in = Wo; outp = WoT; K = 1024; Nsrc = 512; NB = 512; noff = 0; }
        else if (t < 3072) { t -= 2048; in = W1; outp = W1T; K = 512; Nsrc = 2048; NB = 2048; noff = 0; }
        else { t -= 3072; in = W2; outp = W2T; K = 2048; Nsrc = 512; NB = 512; noff = 0; }
        int tilesX = Nsrc >> 5;
        int bx = t % tilesX, by = t / tilesX;
        int x0 = bx * 32, y0 = by * 32;
        __shared__ float tile[32][33];
        int tx = tid & 31, ty = tid >> 5;  // 32 x 8
#pragma unroll
        for (int r = 0; r < 4; r++) {
            int y = y0 + ty + r * 8;       // k index
            tile[ty + r * 8][tx] = in[(size_t)y * Nsrc + x0 + tx];
        }
        __syncthreads();
#pragma unroll
        for (int r = 0; r < 4; r++) {
            int n = x0 + ty + r * 8;       // source col
            int k = y0 + tx;
            outp[(((size_t)(k >> 3) * NB + noff + n) << 3) + (k & 7)] = f2bf(tile[tx][ty + r * 8]);
        }
    } else if (blk < 8192) {
        // pack F[16384][512] -> Fb panels (reads contiguous, writes strided->L2)
        int gi = (blk - 4096) * 256 + tid;   // 16384*64 slots
        int row = gi >> 6, p = gi & 63;
        const float4* src = (const float4*)(F + (size_t)row * 512 + p * 8);
        float4 a = src[0], c = src[1];
        uint32_t w0 = f2bf(a.x) | ((uint32_t)f2bf(a.y) << 16);
        uint32_t w1 = f2bf(a.z) | ((uint32_t)f2bf(a.w) << 16);
        uint32_t w2 = f2bf(c.x) | ((uint32_t)f2bf(c.y) << 16);
        uint32_t w3 = f2bf(c.z) | ((uint32_t)f2bf(c.w) << 16);
        ((uint4*)Fb)[(size_t)p * 16384 + row] = make_uint4(w0, w1, w2, w3);
    } else if (blk < 8204) {
        int i = (blk - 8192) * 256 + tid;
        if (i < 1024) bqkv[i] = bq[i];
        else if (i < 2048) bqkv[i] = bk[i - 1024];
        else if (i < 3072) bqkv[i] = bv[i - 2048];
    } else {
        // ---- KNN top-20 (1 wave per query), packed-argmin (R3, verified) ----
        int wv = (blk - 8204) * 4 + (tid >> 6);
        int l = tid & 63;
        int b = wv >> 10, n = wv & 1023;
        const float* vb = verts + (size_t)b * 1024 * 3;
        float qx = vb[n * 3 + 0], qy = vb[n * 3 + 1], qz = vb[n * 3 + 2];
        float q2 = qx * qx + qy * qy + qz * qz;
        float pd[16];
#pragma unroll
        for (int t = 0; t < 16; t++) {
            int p = l + 64 * t;
            float px = vb[p * 3 + 0], py = vb[p * 3 + 1], pz = vb[p * 3 + 2];
            float p2 = px * px + py * py + pz * pz;
            float dot = qx * px + qy * py + qz * pz;
            float dv = q2 + p2 - 2.f * dot + 1.0f;
            uint32_t bits = (__float_as_uint(dv) & ~0xFu) | (uint32_t)t;
            pd[t] = __uint_as_float(bits);
        }
        int* outp = nbr + (size_t)wv * 20;
        for (int it = 0; it < 20; it++) {
            float m01 = fminf(pd[0], pd[1]),   m23 = fminf(pd[2], pd[3]);
            float m45 = fminf(pd[4], pd[5]),   m67 = fminf(pd[6], pd[7]);
            float m89 = fminf(pd[8], pd[9]),   mab = fminf(pd[10], pd[11]);
            float mcd = fminf(pd[12], pd[13]), mef = fminf(pd[14], pd[15]);
            float m = fminf(fminf(fminf(m01, m23), fminf(m45, m67)),
                            fminf(fminf(m89, mab), fminf(mcd, mef)));
            m = fminf(m, dpp_get<0x124>(m));
            m = fminf(m, dpp_get<0x128>(m));
            m = fminf(m, dpp_get<0xB1>(m));
            m = fminf(m, dpp_get<0x4E>(m));
            m = fminf(m, __shfl_xor(m, 16));
            m = fminf(m, __shfl_xor(m, 32));
            bool mine = false;
#pragma unroll
            for (int t = 0; t < 16; t++) mine |= (pd[t] == m);
            unsigned long long bal = __ballot(mine);
            int wl = (int)__builtin_ctzll(bal);
            if (l == wl) {
#pragma unroll
                for (int t = 0; t < 16; t++) if (pd[t] == m) pd[t] = 3.4e38f;
            }
            if (l == 0) outp[it] = ((int)(__float_as_uint(m) & 15u)) * 64 + wl;
        }
    }
}

// ---------------------------------------------------------------- GEMM ----
// C[M,N] = A[M,K] * B[K,N], packed-panel operands. bf16 in, fp32 accum,
// MFMA 16x16x32, BK=32, 128x128 tile. R6 change: B fragments load DIRECTLY
// global->VGPR (B matrices are 1-6MB, L2-resident; the packed panel layout
// makes each wave's B frag a coalesced 256B b128 read at exactly the
// fragment slot). Only A is LDS-staged (DMA double-buffer). This halves LDS
// read traffic + halves staging DMA — per R4's post-mortem the LDS port and
// sync, not staging instructions, were the contended resource (MfmaUtil 24%
// vs VALUBusy 45%). Sync hazards: sched_barrier(0) pins the DMA issue;
// "memory"-clobbered vmcnt(2) means the 2 in-flight next-tile DMAs are the
// only outstanding VMEM at the wait (B loads are compiler-waited at use,
// and cannot hoist across the memory-clobber asm).
// EPI: 0 bias->bf16 row-major | 1 bias+relu->PACKED bf16 | 3 partial->fp32
template <int EPI>
__global__ __launch_bounds__(256) void gemm_bt(const u16* __restrict__ A,
                                               const u16* __restrict__ BT,
                                               const float* __restrict__ bias,
                                               u16* __restrict__ Cb,
                                               float* __restrict__ Cf,
                                               float* __restrict__ Cf2,
                                               int M, int N, int Klen,
                                               int MA, int NB, int Koff) {
    __shared__ __align__(16) u16 As0[4096], As1[4096];   // 8KB each: [kq][row][8]
    int tid = threadIdx.x;
    int id = blockIdx.y * gridDim.x + blockIdx.x;
    int by = id % gridDim.y, bx = id / gridDim.y;
    int m0 = by * 128, n0 = bx * 128;
    int kz = blockIdx.z;
    const uint4* A4 = (const uint4*)A + (size_t)kz * (Koff >> 3) * MA;
    const uint4* B4 = (const uint4*)BT + (size_t)kz * (Koff >> 3) * NB;
    int w = tid >> 6, l = tid & 63;
    int wr = w >> 1, wc = w & 1, quad = l >> 4, ln = l & 15;
    // A staging: slot i=tid -> (panel q=tid>>7, row tid&127); i=tid+256 -> q+2
    int qA = tid >> 7, rA = tid & 127;
    const uint4* pA0 = A4 + (size_t)qA * MA + m0 + rA;
    const uint4* pA1 = pA0 + 2 * (size_t)MA;
    // B frag base: panel (k>>3)+quad, row n0 + wc*64 + j*16 + ln
    const uint4* pB = B4 + (size_t)quad * NB + n0 + wc * 64 + ln;

    f32x4 acc[4][4];
#pragma unroll
    for (int i = 0; i < 4; i++)
#pragma unroll
        for (int j = 0; j < 4; j++) acc[i][j] = (f32x4){0.f, 0.f, 0.f, 0.f};

#define STAGE(As, ko) do { size_t kq = (size_t)((ko) >> 3);                  \
        GLL16(pA0 + kq * MA, (char*)(As) + tid * 16);                        \
        GLL16(pA1 + kq * MA, (char*)(As) + (tid + 256) * 16);                \
        __builtin_amdgcn_sched_barrier(0); } while (0)
#define COMPUTE(Asb, ko) do {                                                             \
        const bf16x8* Av = (const bf16x8*)(Asb);                                          \
        const uint4* Bq = pB + (size_t)((ko) >> 3) * NB;                                  \
        bf16x8 af[4], bfr[4];                                                             \
        _Pragma("unroll")                                                                 \
        for (int j = 0; j < 4; j++) bfr[j] = *(const bf16x8*)(Bq + j * 16);               \
        _Pragma("unroll")                                                                 \
        for (int i = 0; i < 4; i++) af[i] = Av[quad * 128 + wr * 64 + i * 16 + ln];       \
        _Pragma("unroll")                                                                 \
        for (int i = 0; i < 4; i++)                                                       \
            _Pragma("unroll")                                                             \
            for (int j = 0; j < 4; j++)                                                   \
                acc[i][j] = __builtin_amdgcn_mfma_f32_16x16x32_bf16(af[i], bfr[j], acc[i][j], 0, 0, 0); \
    } while (0)

    int nIter = Klen >> 5;   // even, >= 4 for all shapes used
    STAGE(As0, 0);                                        // 2 DMA in flight
    for (int kt = 0; kt < nIter; kt += 2) {
        STAGE(As1, (kt + 1) * 32);                        // +2 -> 4 in flight
        asm volatile("s_waitcnt vmcnt(2)" ::: "memory");  // tile kt A landed
        __builtin_amdgcn_s_barrier();
        COMPUTE(As0, kt * 32);                            // tile kt
        __builtin_amdgcn_s_barrier();                     // reads of As0 done
        if (kt + 2 < nIter) {
            STAGE(As0, (kt + 2) * 32);
            asm volatile("s_waitcnt vmcnt(2)" ::: "memory");  // tile kt+1 landed
        } else {
            asm volatile("s_waitcnt vmcnt(0)" ::: "memory");
        }
        __builtin_amdgcn_s_barrier();
        COMPUTE(As1, (kt + 1) * 32);                      // tile kt+1
        __builtin_amdgcn_s_barrier();                     // reads of As1 done
    }
#undef STAGE
#undef COMPUTE

    float* Cfz = (EPI == 3) ? (kz ? Cf2 : Cf) : Cf;
    // epilogue: row = m0+wr*64+i*16+quad*4+r, col = n0+wc*64+j*16+ln
#pragma unroll
    for (int i = 0; i < 4; i++) {
        int row_base = m0 + wr * 64 + i * 16 + quad * 4;
#pragma unroll
        for (int j = 0; j < 4; j++) {
            int col = n0 + wc * 64 + j * 16 + ln;
            float bb = (EPI == 3) ? 0.f : bias[col];
#pragma unroll
            for (int r = 0; r < 4; r++) {
                int row = row_base + r;
                float v = acc[i][j][r] + bb;
                if (EPI == 0) Cb[(size_t)row * N + col] = f2bf(v);
                else if (EPI == 1)  // packed output (next GEMM's A operand)
                    Cb[(((size_t)(col >> 3) * M + row) << 3) + (col & 7)] = f2bf(v > 0.f ? v : 0.f);
                else Cfz[(size_t)row * N + col] = v;
            }
        }
    }
}

// ----------------------------------------------------- sparse attention ----
// EXACT proven version (R4/R5: 89.5us, 92 VGPR, absmax 0.03125). Two phases,
// __shfl_xor 16-lane reduce in phase 1 (its lgkmcnt waits act as scheduling
// fences that stop the compiler from hoisting 20 iterations' loads -> keeps
// register pressure low). THREE failed perturbations (R1 fuse: 152 VGPR;
// R2 DPP+exp-in-loop: 196 VGPR; R6 launch_bounds(256,8): 32 VGPR + 713MB
// scratch spill, 400us). DO NOT TOUCH. XCD swizzle proven (FETCH 305->111MB).
__global__ __launch_bounds__(256) void attn_kernel(const u16* __restrict__ QKV,
                                                   const int* __restrict__ nbr,
                                                   u16* __restrict__ outA) {
    int tid = threadIdx.x;
    int bid = blockIdx.x;
    int swz = (bid & 7) * 512 + (bid >> 3);   // 4096 blocks, bijective
    int wv = swz * 4 + (tid >> 6);  // b*1024+n
    int l = tid & 63;
    int h = l >> 4, sx = l & 15;
    int bbase = (wv >> 10) << 10;

    int nv = 0;
    if (l < 20) nv = nbr[(size_t)wv * 20 + l];

    const uint32_t* qp = (const uint32_t*)(QKV + (size_t)wv * 3072 + h * 256 + sx * 16);
    uint32_t qw[8];
    *(uint4*)(qw) = *(const uint4*)qp;
    *(uint4*)(qw + 4) = *(const uint4*)(qp + 4);
    float qf[16];
#pragma unroll
    for (int i = 0; i < 8; i++) { qf[2 * i] = bfbits_lo(qw[i]); qf[2 * i + 1] = bfbits_hi(qw[i]); }

    float wj[20];
#pragma unroll
    for (int j = 0; j < 20; j++) {
        int m = __shfl(nv, j);
        const uint32_t* kp = (const uint32_t*)(QKV + (size_t)(bbase + m) * 3072 + 1024 + h * 256 + sx * 16);
        uint32_t kw[8];
        *(uint4*)(kw) = *(const uint4*)kp;
        *(uint4*)(kw + 4) = *(const uint4*)(kp + 4);
        float acc = 0.f;
#pragma unroll
        for (int i = 0; i < 8; i++) {
            acc += qf[2 * i] * bfbits_lo(kw[i]);
            acc += qf[2 * i + 1] * bfbits_hi(kw[i]);
        }
#pragma unroll
        for (int off = 1; off < 16; off <<= 1) acc += __shfl_xor(acc, off);
        wj[j] = acc * 0.0625f;
    }
    float ssum = 0.f;
#pragma unroll
    for (int j = 0; j < 20; j++) { wj[j] = __expf(wj[j]); ssum += wj[j]; }
    float inv = 1.f / ssum;

    float o[16];
#pragma unroll
    for (int i = 0; i < 16; i++) o[i] = 0.f;
#pragma unroll
    for (int j = 0; j < 20; j++) {
        int m = __shfl(nv, j);
        const uint32_t* vp = (const uint32_t*)(QKV + (size_t)(bbase + m) * 3072 + 2048 + h * 256 + sx * 16);
        uint32_t vw[8];
        *(uint4*)(vw) = *(const uint4*)vp;
        *(uint4*)(vw + 4) = *(const uint4*)(vp + 4);
        float ww = wj[j] * inv;
#pragma unroll
        for (int i = 0; i < 8; i++) {
            o[2 * i] += ww * bfbits_lo(vw[i]);
            o[2 * i + 1] += ww * bfbits_hi(vw[i]);
        }
    }
    uint32_t ow[8];
#pragma unroll
    for (int i = 0; i < 8; i++) ow[i] = f2bf(o[2 * i]) | ((uint32_t)f2bf(o[2 * i + 1]) << 16);
    // packed store: cols h*256+sx*16 .. +15 -> panels h*32+sx*2, h*32+sx*2+1, row wv
    size_t slot = (size_t)(h * 32 + sx * 2) * 16384 + wv;
    ((uint4*)outA)[slot] = make_uint4(ow[0], ow[1], ow[2], ow[3]);
    ((uint4*)outA)[slot + 16384] = make_uint4(ow[4], ow[5], ow[6], ow[7]);
}

// ------------------------------------------------- LN over split-K sum ----
// LN(P0 + P1 + res + biasv) -> Yf fp32 (+ Yb PACKED bf16 if WB)
template <int WB>
__global__ __launch_bounds__(256) void ln12p_kernel(const float* __restrict__ P0,
                                                    const float* __restrict__ P1,
                                                    const float* __restrict__ res,
                                                    const float* __restrict__ biasv,
                                                    const float* __restrict__ g,
                                                    const float* __restrict__ bparm,
                                                    float* __restrict__ Yf,
                                                    u16* __restrict__ Yb) {
    int tid = threadIdx.x;
    int row = blockIdx.x * 4 + (tid >> 6);
    int l = tid & 63;
    size_t base = (size_t)row * 512;
    const float4* p0 = (const float4*)(P0 + base) + l * 2;
    const float4* p1 = (const float4*)(P1 + base) + l * 2;
    const float4* rr = (const float4*)(res + base) + l * 2;
    const float4* bv = (const float4*)biasv + l * 2;
    float xs[8];
#pragma unroll
    for (int h = 0; h < 2; h++) {
        float4 a = p0[h], b = p1[h], c = rr[h], d = bv[h];
        xs[4 * h + 0] = a.x + b.x + c.x + d.x;
        xs[4 * h + 1] = a.y + b.y + c.y + d.y;
        xs[4 * h + 2] = a.z + b.z + c.z + d.z;
        xs[4 * h + 3] = a.w + b.w + c.w + d.w;
    }
    float s = 0.f;
#pragma unroll
    for (int i = 0; i < 8; i++) s += xs[i];
#pragma unroll
    for (int off = 32; off >= 1; off >>= 1) s += __shfl_xor(s, off);
    float mu = s * (1.f / 512.f);
    float q = 0.f;
#pragma unroll
    for (int i = 0; i < 8; i++) { float dd = xs[i] - mu; q += dd * dd; }
#pragma unroll
    for (int off = 32; off >= 1; off >>= 1) q += __shfl_xor(q, off);
    float var = q * (1.f / 512.f);
    float rs = rsqrtf(var + 1e-5f);
    const float4* gp = (const float4*)g + l * 2;
    const float4* bp = (const float4*)bparm + l * 2;
    float4 g0 = gp[0], g1 = gp[1], b0 = bp[0], b1 = bp[1];
    float gg[8] = {g0.x, g0.y, g0.z, g0.w, g1.x, g1.y, g1.z, g1.w};
    float bbv[8] = {b0.x, b0.y, b0.z, b0.w, b1.x, b1.y, b1.z, b1.w};
    float y[8];
#pragma unroll
    for (int i = 0; i < 8; i++) y[i] = (xs[i] - mu) * rs * gg[i] + bbv[i];
    float4* yo = (float4*)(Yf + base) + l * 2;
    yo[0] = make_float4(y[0], y[1], y[2], y[3]);
    yo[1] = make_float4(y[4], y[5], y[6], y[7]);
    if (WB) {
        uint32_t w0 = f2bf(y[0]) | ((uint32_t)f2bf(y[1]) << 16);
        uint32_t w1 = f2bf(y[2]) | ((uint32_t)f2bf(y[3]) << 16);
        uint32_t w2 = f2bf(y[4]) | ((uint32_t)f2bf(y[5]) << 16);
        uint32_t w3 = f2bf(y[6]) | ((uint32_t)f2bf(y[7]) << 16);
        // packed: lane l holds k = l*8..l*8+7 of this row -> panel l
        ((uint4*)Yb)[(size_t)l * 16384 + row] = make_uint4(w0, w1, w2, w3);
    }
}

// ------------------------------------------------------------ launcher ----
extern "C" void kernel_launch(void* const* d_in, const int* in_sizes, int n_in,
                              void* d_out, int out_size, void* d_ws, size_t ws_size,
                              hipStream_t stream) {
    const float* verts = (const float*)d_in[0];
    const float* F = (const float*)d_in[1];
    const float* Wq = (const float*)d_in[2];
    const float* bq = (const float*)d_in[3];
    const float* Wk = (const float*)d_in[4];
    const float* bk = (const float*)d_in[5];
    const float* Wv = (const float*)d_in[6];
    const float* bv = (const float*)d_in[7];
    const float* Wo = (const float*)d_in[8];
    const float* bo = (const float*)d_in[9];
    const float* ln1g = (const float*)d_in[10];
    const float* ln1b = (const float*)d_in[11];
    const float* W1 = (const float*)d_in[12];
    const float* b1 = (const float*)d_in[13];
    const float* W2 = (const float*)d_in[14];
    const float* b2 = (const float*)d_in[15];
    const float* ln2g = (const float*)d_in[16];
    const float* ln2b = (const float*)d_in[17];
    float* out = (float*)d_out;

    char* ws = (char*)d_ws;
    // arena (lifetime-overlapped), ~177.5 MB:
    u16* QKV = (u16*)(ws);                         // [0, 96MB)  G1 -> attn (row-major)
    float* Q0 = (float*)(ws);                      // [0, 32MB)  G2 partial 0 -> LN1
    float* Q1 = (float*)(ws + 33554432);           // [32, 64MB) G2 partial 1 -> LN1
    u16* Hb = (u16*)(ws);                          // [0, 64MB)  G3 -> G4 (packed)
    float* P1 = (float*)(ws + 67108864);           // [64, 96MB) G4 partial 1 -> LN2
    u16* ATT = (u16*)(ws + 100663296);             // [96, 128MB) attn -> G2 (packed)
    u16* xb = ATT;                                 //   reuse: LN1 -> G3 (packed)
    float* P0 = (float*)(ws + 100663296);          //   reuse: G4 partial 0 -> LN2
    u16* Fb = (u16*)(ws + 134217728);              // [128, 144.8MB) prep -> G1 (packed)
    float* X32 = (float*)(ws + 134217728);         //   reuse: LN1 -> LN2 (33.5MB)
    char* wsw = ws + 167772160;
    u16* WqkvT = (u16*)(wsw);                      // 3,145,728 (packed)
    u16* WoT = (u16*)(wsw + 3145728);              // 1,048,576 (packed)
    u16* W1T = (u16*)(wsw + 4194304);              // 2,097,152 (packed)
    u16* W2T = (u16*)(wsw + 6291456);              // 2,097,152 (packed)
    float* bqkv = (float*)(wsw + 8388608);         // 16,384 (padded)
    int* nbr = (int*)(wsw + 8404992);              // 1,310,720

    // PREP (one dispatch): transposes+pack + F pack + bias + KNN
    prep_kernel<<<12300, 256, 0, stream>>>(verts, F, Wq, Wk, Wv, Wo, W1, W2,
                                           bq, bk, bv, WqkvT, WoT, W1T, W2T,
                                           bqkv, Fb, nbr);
    // G1: QKV = Fb @ Wqkv + bias -> bf16 row-major [16384, 3072]
    gemm_bt<0><<<dim3(24, 128, 1), 256, 0, stream>>>(Fb, WqkvT, bqkv, QKV, nullptr, nullptr,
                                                     16384, 3072, 512, 16384, 3072, 0);
    // sparse attention -> ATT packed [16384, 1024]
    attn_kernel<<<4096, 256, 0, stream>>>(QKV, nbr, ATT);
    // G2 split-K x2: Q0/Q1 = ATT @ Wo (partials) [16384, 512]
    gemm_bt<3><<<dim3(4, 128, 2), 256, 0, stream>>>(ATT, WoT, nullptr, nullptr, Q0, Q1,
                                                    16384, 512, 512, 16384, 512, 512);
    // LN1: LN(Q0+Q1+bo+F) -> X32 fp32 + xb packed bf16
    ln12p_kernel<1><<<4096, 256, 0, stream>>>(Q0, Q1, F, bo, ln1g, ln1b, X32, xb);
    // G3: Hb = relu(xb @ W1 + b1) -> packed bf16 [16384, 2048]
    gemm_bt<1><<<dim3(16, 128, 1), 256, 0, stream>>>(xb, W1T, b1, Hb, nullptr, nullptr,
                                                     16384, 2048, 512, 16384, 2048, 0);
    // G4 split-K x2: P0/P1 = Hb @ W2 (partials) [16384, 512]
    gemm_bt<3><<<dim3(4, 128, 2), 256, 0, stream>>>(Hb, W2T, nullptr, nullptr, P0, P1,
                                                    16384, 512, 1024, 16384, 512, 1024);
    // LN2: LN(P0+P1+b2+X32) -> out
    ln12p_kernel<0><<<4096, 256, 0, stream>>>(P0, P1, X32, b2, ln2g, ln2b, out, nullptr);
}

// Round 8
// 499.951 us; speedup vs baseline: 1.7465x; 1.0696x over previous
//
#include <hip/hip_runtime.h>
#include <stdint.h>

typedef uint16_t u16;
typedef __bf16 bf16x8 __attribute__((ext_vector_type(8)));
typedef float f32x4 __attribute__((ext_vector_type(4)));

#define DEV static __device__ __forceinline__

DEV float bfbits_lo(uint32_t w) { union { uint32_t i; float f; } v; v.i = w << 16; return v.f; }
DEV float bfbits_hi(uint32_t w) { union { uint32_t i; float f; } v; v.i = w & 0xffff0000u; return v.f; }
DEV u16 f2bf(float f) {
    union { float f; uint32_t i; } v; v.f = f;
    uint32_t x = v.i;
    uint32_t r = (x + 0x7fffu + ((x >> 16) & 1u)) >> 16;  // RNE
    return (u16)r;
}

// DPP cross-lane permute within each 16-lane row: returns permuted value.
// CTRL: 0x124=row_ror:4, 0x128=row_ror:8, 0xB1=quad_perm xor1, 0x4E=quad_perm xor2
template <int CTRL>
DEV float dpp_get(float x) {
    union { float f; int i; } a, r;
    a.f = x;
    r.i = __builtin_amdgcn_update_dpp(0, a.i, CTRL, 0xf, 0xf, false);
    return r.f;
}

// async global->LDS DMA, 16B per lane. LDS dest must be wave-uniform base +
// lane*16 (HW semantics); our staging slots (base + tid*16) satisfy this.
#define GLL16(g, l)                                                        \
    __builtin_amdgcn_global_load_lds(                                      \
        (const __attribute__((address_space(1))) uint32_t*)(g),            \
        (__attribute__((address_space(3))) uint32_t*)(l), 16, 0, 0)

// Packed operand layout ("panels"): element (row, k) of a [R x K] matrix
// lives at u16 index ((k>>3)*R + row)*8 + (k&7)  == uint4 slot (k>>3)*R + row.
// A wave staging 64 consecutive rows of one panel reads 1KB CONTIGUOUS.

// ------------------------------------------------------------- PREP ----
// blocks 0..4095: weight transpose+pack; 4096..8191: F pack; 8192..8203:
// bias concat; 8204..12299: KNN.
__global__ __launch_bounds__(256) void prep_kernel(
    const float* __restrict__ verts, const float* __restrict__ F,
    const float* __restrict__ Wq, const float* __restrict__ Wk,
    const float* __restrict__ Wv, const float* __restrict__ Wo,
    const float* __restrict__ W1, const float* __restrict__ W2,
    const float* __restrict__ bq, const float* __restrict__ bk,
    const float* __restrict__ bv,
    u16* __restrict__ WqkvT, u16* __restrict__ WoT,
    u16* __restrict__ W1T, u16* __restrict__ W2T,
    float* __restrict__ bqkv, u16* __restrict__ Fb, int* __restrict__ nbr) {
    int blk = blockIdx.x;
    int tid = threadIdx.x;
    if (blk < 4096) {
        // transpose W[K][Nsrc] -> packed BT panels [(k>>3)*NB + noff + n][k&7]
        const float* in; u16* outp; int K, Nsrc, NB, noff, t = blk;
        if (t < 512) { in = Wq; outp = WqkvT; K = 512; Nsrc = 1024; NB = 3072; noff = 0; }
        else if (t < 1024) { t -= 512; in = Wk; outp = WqkvT; K = 512; Nsrc = 1024; NB = 3072; noff = 1024; }
        else if (t < 1536) { t -= 1024; in = Wv; outp = WqkvT; K = 512; Nsrc = 1024; NB = 3072; noff = 2048; }
        else if (t < 2048) { t -= 1536; in = Wo; outp = WoT; K = 1024; Nsrc = 512; NB = 512; noff = 0; }
        else if (t < 3072) { t -= 2048; in = W1; outp = W1T; K = 512; Nsrc = 2048; NB = 2048; noff = 0; }
        else { t -= 3072; in = W2; outp = W2T; K = 2048; Nsrc = 512; NB = 512; noff = 0; }
        int tilesX = Nsrc >> 5;
        int bx = t % tilesX, by = t / tilesX;
        int x0 = bx * 32, y0 = by * 32;
        __shared__ float tile[32][33];
        int tx = tid & 31, ty = tid >> 5;  // 32 x 8
#pragma unroll
        for (int r = 0; r < 4; r++) {
            int y = y0 + ty + r * 8;       // k index
            tile[ty + r * 8][tx] = in[(size_t)y * Nsrc + x0 + tx];
        }
        __syncthreads();
#pragma unroll
        for (int r = 0; r < 4; r++) {
            int n = x0 + ty + r * 8;       // source col
            int k = y0 + tx;
            outp[(((size_t)(k >> 3) * NB + noff + n) << 3) + (k & 7)] = f2bf(tile[tx][ty + r * 8]);
        }
    } else if (blk < 8192) {
        // pack F[16384][512] -> Fb panels (reads contiguous, writes strided->L2)
        int gi = (blk - 4096) * 256 + tid;   // 16384*64 slots
        int row = gi >> 6, p = gi & 63;
        const float4* src = (const float4*)(F + (size_t)row * 512 + p * 8);
        float4 a = src[0], c = src[1];
        uint32_t w0 = f2bf(a.x) | ((uint32_t)f2bf(a.y) << 16);
        uint32_t w1 = f2bf(a.z) | ((uint32_t)f2bf(a.w) << 16);
        uint32_t w2 = f2bf(c.x) | ((uint32_t)f2bf(c.y) << 16);
        uint32_t w3 = f2bf(c.z) | ((uint32_t)f2bf(c.w) << 16);
        ((uint4*)Fb)[(size_t)p * 16384 + row] = make_uint4(w0, w1, w2, w3);
    } else if (blk < 8204) {
        int i = (blk - 8192) * 256 + tid;
        if (i < 1024) bqkv[i] = bq[i];
        else if (i < 2048) bqkv[i] = bk[i - 1024];
        else if (i < 3072) bqkv[i] = bv[i - 2048];
    } else {
        // ---- KNN top-20 (1 wave per query), packed-argmin (R3, verified) ----
        int wv = (blk - 8204) * 4 + (tid >> 6);
        int l = tid & 63;
        int b = wv >> 10, n = wv & 1023;
        const float* vb = verts + (size_t)b * 1024 * 3;
        float qx = vb[n * 3 + 0], qy = vb[n * 3 + 1], qz = vb[n * 3 + 2];
        float q2 = qx * qx + qy * qy + qz * qz;
        float pd[16];
#pragma unroll
        for (int t = 0; t < 16; t++) {
            int p = l + 64 * t;
            float px = vb[p * 3 + 0], py = vb[p * 3 + 1], pz = vb[p * 3 + 2];
            float p2 = px * px + py * py + pz * pz;
            float dot = qx * px + qy * py + qz * pz;
            float dv = q2 + p2 - 2.f * dot + 1.0f;
            uint32_t bits = (__float_as_uint(dv) & ~0xFu) | (uint32_t)t;
            pd[t] = __uint_as_float(bits);
        }
        int* outp = nbr + (size_t)wv * 20;
        for (int it = 0; it < 20; it++) {
            float m01 = fminf(pd[0], pd[1]),   m23 = fminf(pd[2], pd[3]);
            float m45 = fminf(pd[4], pd[5]),   m67 = fminf(pd[6], pd[7]);
            float m89 = fminf(pd[8], pd[9]),   mab = fminf(pd[10], pd[11]);
            float mcd = fminf(pd[12], pd[13]), mef = fminf(pd[14], pd[15]);
            float m = fminf(fminf(fminf(m01, m23), fminf(m45, m67)),
                            fminf(fminf(m89, mab), fminf(mcd, mef)));
            m = fminf(m, dpp_get<0x124>(m));
            m = fminf(m, dpp_get<0x128>(m));
            m = fminf(m, dpp_get<0xB1>(m));
            m = fminf(m, dpp_get<0x4E>(m));
            m = fminf(m, __shfl_xor(m, 16));
            m = fminf(m, __shfl_xor(m, 32));
            bool mine = false;
#pragma unroll
            for (int t = 0; t < 16; t++) mine |= (pd[t] == m);
            unsigned long long bal = __ballot(mine);
            int wl = (int)__builtin_ctzll(bal);
            if (l == wl) {
#pragma unroll
                for (int t = 0; t < 16; t++) if (pd[t] == m) pd[t] = 3.4e38f;
            }
            if (l == 0) outp[it] = ((int)(__float_as_uint(m) & 15u)) * 64 + wl;
        }
    }
}

// ---------------------------------------------------------------- GEMM ----
// C[M,N] = A[M,K] * B[K,N], both operands packed-panel. bf16 in, fp32 accum,
// MFMA 16x16x32, BK=32, 128x128 tile. BOTH A and B staged via
// global_load_lds DMA (16B/lane), counted vmcnt(4) 2-phase schedule — the
// proven-best GEMM config (R5 bench: 522.2us total). R7's B-direct-to-VGPR
// variant REGRESSED (+12us total: B loads at L2 latency land on the compute
// critical path; LDS sharing of B across 4 waves is cheaper). 2-phase
// structure is at its documented ceiling; do not micro-tune further.
// EPI: 0 bias->bf16 row-major | 1 bias+relu->PACKED bf16 | 3 plain->fp32
template <int EPI>
__global__ __launch_bounds__(256) void gemm_bt(const u16* __restrict__ A,
                                               const u16* __restrict__ BT,
                                               const float* __restrict__ bias,
                                               u16* __restrict__ Cb,
                                               float* __restrict__ Cf,
                                               float* __restrict__ Cf2,
                                               int M, int N, int Klen,
                                               int MA, int NB, int Koff) {
    __shared__ __align__(16) u16 As0[4096], As1[4096];   // 8KB each: [kq][row][8]
    __shared__ __align__(16) u16 Bs0[4096], Bs1[4096];
    int tid = threadIdx.x;
    int id = blockIdx.y * gridDim.x + blockIdx.x;
    int by = id % gridDim.y, bx = id / gridDim.y;
    int m0 = by * 128, n0 = bx * 128;
    int kz = blockIdx.z;
    const uint4* A4 = (const uint4*)A + (size_t)kz * (Koff >> 3) * MA;
    const uint4* B4 = (const uint4*)BT + (size_t)kz * (Koff >> 3) * NB;
    int w = tid >> 6, l = tid & 63;
    int wr = w >> 1, wc = w & 1, quad = l >> 4, ln = l & 15;
    // staging: slot i=tid -> (panel q=tid>>7, row tid&127); i=tid+256 -> q+2
    int qA = tid >> 7, rA = tid & 127;
    const uint4* pA0 = A4 + (size_t)qA * MA + m0 + rA;
    const uint4* pA1 = pA0 + 2 * (size_t)MA;
    const uint4* pB0 = B4 + (size_t)qA * NB + n0 + rA;
    const uint4* pB1 = pB0 + 2 * (size_t)NB;

    f32x4 acc[4][4];
#pragma unroll
    for (int i = 0; i < 4; i++)
#pragma unroll
        for (int j = 0; j < 4; j++) acc[i][j] = (f32x4){0.f, 0.f, 0.f, 0.f};

#define STAGE(As, Bs, ko) do { size_t kq = (size_t)((ko) >> 3);              \
        GLL16(pA0 + kq * MA, (char*)(As) + tid * 16);                        \
        GLL16(pA1 + kq * MA, (char*)(As) + (tid + 256) * 16);                \
        GLL16(pB0 + kq * NB, (char*)(Bs) + tid * 16);                        \
        GLL16(pB1 + kq * NB, (char*)(Bs) + (tid + 256) * 16); } while (0)
#define COMPUTE(Asb, Bsb) do {                                                            \
        const bf16x8* Av = (const bf16x8*)(Asb);                                          \
        const bf16x8* Bv = (const bf16x8*)(Bsb);                                          \
        bf16x8 af[4], bfr[4];                                                             \
        _Pragma("unroll")                                                                 \
        for (int i = 0; i < 4; i++) af[i] = Av[quad * 128 + wr * 64 + i * 16 + ln];       \
        _Pragma("unroll")                                                                 \
        for (int j = 0; j < 4; j++) bfr[j] = Bv[quad * 128 + wc * 64 + j * 16 + ln];      \
        _Pragma("unroll")                                                                 \
        for (int i = 0; i < 4; i++)                                                       \
            _Pragma("unroll")                                                             \
            for (int j = 0; j < 4; j++)                                                   \
                acc[i][j] = __builtin_amdgcn_mfma_f32_16x16x32_bf16(af[i], bfr[j], acc[i][j], 0, 0, 0); \
    } while (0)

    int nIter = Klen >> 5;   // even, >= 4 for all shapes used
    STAGE(As0, Bs0, 0);                                   // 4 loads in flight
    for (int kt = 0; kt < nIter; kt += 2) {
        STAGE(As1, Bs1, (kt + 1) * 32);                   // +4 -> 8 in flight
        asm volatile("s_waitcnt vmcnt(4)" ::: "memory");  // tile kt landed
        __builtin_amdgcn_s_barrier();
        COMPUTE(As0, Bs0);                                // tile kt
        __builtin_amdgcn_s_barrier();                     // reads of As0/Bs0 done
        if (kt + 2 < nIter) {
            STAGE(As0, Bs0, (kt + 2) * 32);               // +4 -> 8 in flight
            asm volatile("s_waitcnt vmcnt(4)" ::: "memory");  // tile kt+1 landed
        } else {
            asm volatile("s_waitcnt vmcnt(0)" ::: "memory");
        }
        __builtin_amdgcn_s_barrier();
        COMPUTE(As1, Bs1);                                // tile kt+1
        __builtin_amdgcn_s_barrier();                     // reads of As1/Bs1 done
    }
#undef STAGE
#undef COMPUTE

    float* Cfz = (EPI == 3) ? (kz ? Cf2 : Cf) : Cf;
    // epilogue: row = m0+wr*64+i*16+quad*4+r, col = n0+wc*64+j*16+ln
#pragma unroll
    for (int i = 0; i < 4; i++) {
        int row_base = m0 + wr * 64 + i * 16 + quad * 4;
#pragma unroll
        for (int j = 0; j < 4; j++) {
            int col = n0 + wc * 64 + j * 16 + ln;
            float bb = (EPI == 3) ? 0.f : bias[col];
#pragma unroll
            for (int r = 0; r < 4; r++) {
                int row = row_base + r;
                float v = acc[i][j][r] + bb;
                if (EPI == 0) Cb[(size_t)row * N + col] = f2bf(v);
                else if (EPI == 1)  // packed output (next GEMM's A operand)
                    Cb[(((size_t)(col >> 3) * M + row) << 3) + (col & 7)] = f2bf(v > 0.f ? v : 0.f);
                else Cfz[(size_t)row * N + col] = v;
            }
        }
    }
}

// ----------------------------------------------------- sparse attention ----
// EXACT proven version (89.4us, 92 VGPR, absmax 0.03125). Two phases,
// __shfl_xor 16-lane reduce in phase 1 (its lgkmcnt waits act as scheduling
// fences that stop the compiler from hoisting 20 iterations' loads -> keeps
// register pressure low). THREE failed perturbations (R1 fuse: 152 VGPR;
// R2 DPP+exp-in-loop: 196 VGPR; R6 launch_bounds(256,8): 32 VGPR + 713MB
// scratch spill, 400us). DO NOT TOUCH. XCD swizzle proven (FETCH 305->111MB).
__global__ __launch_bounds__(256) void attn_kernel(const u16* __restrict__ QKV,
                                                   const int* __restrict__ nbr,
                                                   u16* __restrict__ outA) {
    int tid = threadIdx.x;
    int bid = blockIdx.x;
    int swz = (bid & 7) * 512 + (bid >> 3);   // 4096 blocks, bijective
    int wv = swz * 4 + (tid >> 6);  // b*1024+n
    int l = tid & 63;
    int h = l >> 4, sx = l & 15;
    int bbase = (wv >> 10) << 10;

    int nv = 0;
    if (l < 20) nv = nbr[(size_t)wv * 20 + l];

    const uint32_t* qp = (const uint32_t*)(QKV + (size_t)wv * 3072 + h * 256 + sx * 16);
    uint32_t qw[8];
    *(uint4*)(qw) = *(const uint4*)qp;
    *(uint4*)(qw + 4) = *(const uint4*)(qp + 4);
    float qf[16];
#pragma unroll
    for (int i = 0; i < 8; i++) { qf[2 * i] = bfbits_lo(qw[i]); qf[2 * i + 1] = bfbits_hi(qw[i]); }

    float wj[20];
#pragma unroll
    for (int j = 0; j < 20; j++) {
        int m = __shfl(nv, j);
        const uint32_t* kp = (const uint32_t*)(QKV + (size_t)(bbase + m) * 3072 + 1024 + h * 256 + sx * 16);
        uint32_t kw[8];
        *(uint4*)(kw) = *(const uint4*)kp;
        *(uint4*)(kw + 4) = *(const uint4*)(kp + 4);
        float acc = 0.f;
#pragma unroll
        for (int i = 0; i < 8; i++) {
            acc += qf[2 * i] * bfbits_lo(kw[i]);
            acc += qf[2 * i + 1] * bfbits_hi(kw[i]);
        }
#pragma unroll
        for (int off = 1; off < 16; off <<= 1) acc += __shfl_xor(acc, off);
        wj[j] = acc * 0.0625f;
    }
    float ssum = 0.f;
#pragma unroll
    for (int j = 0; j < 20; j++) { wj[j] = __expf(wj[j]); ssum += wj[j]; }
    float inv = 1.f / ssum;

    float o[16];
#pragma unroll
    for (int i = 0; i < 16; i++) o[i] = 0.f;
#pragma unroll
    for (int j = 0; j < 20; j++) {
        int m = __shfl(nv, j);
        const uint32_t* vp = (const uint32_t*)(QKV + (size_t)(bbase + m) * 3072 + 2048 + h * 256 + sx * 16);
        uint32_t vw[8];
        *(uint4*)(vw) = *(const uint4*)vp;
        *(uint4*)(vw + 4) = *(const uint4*)(vp + 4);
        float ww = wj[j] * inv;
#pragma unroll
        for (int i = 0; i < 8; i++) {
            o[2 * i] += ww * bfbits_lo(vw[i]);
            o[2 * i + 1] += ww * bfbits_hi(vw[i]);
        }
    }
    uint32_t ow[8];
#pragma unroll
    for (int i = 0; i < 8; i++) ow[i] = f2bf(o[2 * i]) | ((uint32_t)f2bf(o[2 * i + 1]) << 16);
    // packed store: cols h*256+sx*16 .. +15 -> panels h*32+sx*2, h*32+sx*2+1, row wv
    size_t slot = (size_t)(h * 32 + sx * 2) * 16384 + wv;
    ((uint4*)outA)[slot] = make_uint4(ow[0], ow[1], ow[2], ow[3]);
    ((uint4*)outA)[slot + 16384] = make_uint4(ow[4], ow[5], ow[6], ow[7]);
}

// ------------------------------------------------- LN over GEMM output ----
// LN((NP==2 ? P0+P1 : P0) + res + biasv) -> Yf fp32 (+ Yb PACKED bf16 if WB)
// R7 change: NP=1 variant — G2/G4 no longer split-K, so only one partial.
template <int WB, int NP>
__global__ __launch_bounds__(256) void ln12p_kernel(const float* __restrict__ P0,
                                                    const float* __restrict__ P1,
                                                    const float* __restrict__ res,
                                                    const float* __restrict__ biasv,
                                                    const float* __restrict__ g,
                                                    const float* __restrict__ bparm,
                                                    float* __restrict__ Yf,
                                                    u16* __restrict__ Yb) {
    int tid = threadIdx.x;
    int row = blockIdx.x * 4 + (tid >> 6);
    int l = tid & 63;
    size_t base = (size_t)row * 512;
    const float4* p0 = (const float4*)(P0 + base) + l * 2;
    const float4* rr = (const float4*)(res + base) + l * 2;
    const float4* bv = (const float4*)biasv + l * 2;
    float xs[8];
#pragma unroll
    for (int h = 0; h < 2; h++) {
        float4 a = p0[h], c = rr[h], d = bv[h];
        xs[4 * h + 0] = a.x + c.x + d.x;
        xs[4 * h + 1] = a.y + c.y + d.y;
        xs[4 * h + 2] = a.z + c.z + d.z;
        xs[4 * h + 3] = a.w + c.w + d.w;
        if constexpr (NP == 2) {
            const float4* p1 = (const float4*)(P1 + base) + l * 2;
            float4 b = p1[h];
            xs[4 * h + 0] += b.x; xs[4 * h + 1] += b.y;
            xs[4 * h + 2] += b.z; xs[4 * h + 3] += b.w;
        }
    }
    float s = 0.f;
#pragma unroll
    for (int i = 0; i < 8; i++) s += xs[i];
#pragma unroll
    for (int off = 32; off >= 1; off >>= 1) s += __shfl_xor(s, off);
    float mu = s * (1.f / 512.f);
    float q = 0.f;
#pragma unroll
    for (int i = 0; i < 8; i++) { float dd = xs[i] - mu; q += dd * dd; }
#pragma unroll
    for (int off = 32; off >= 1; off >>= 1) q += __shfl_xor(q, off);
    float var = q * (1.f / 512.f);
    float rs = rsqrtf(var + 1e-5f);
    const float4* gp = (const float4*)g + l * 2;
    const float4* bp = (const float4*)bparm + l * 2;
    float4 g0 = gp[0], g1 = gp[1], b0 = bp[0], b1 = bp[1];
    float gg[8] = {g0.x, g0.y, g0.z, g0.w, g1.x, g1.y, g1.z, g1.w};
    float bbv[8] = {b0.x, b0.y, b0.z, b0.w, b1.x, b1.y, b1.z, b1.w};
    float y[8];
#pragma unroll
    for (int i = 0; i < 8; i++) y[i] = (xs[i] - mu) * rs * gg[i] + bbv[i];
    float4* yo = (float4*)(Yf + base) + l * 2;
    yo[0] = make_float4(y[0], y[1], y[2], y[3]);
    yo[1] = make_float4(y[4], y[5], y[6], y[7]);
    if (WB) {
        uint32_t w0 = f2bf(y[0]) | ((uint32_t)f2bf(y[1]) << 16);
        uint32_t w1 = f2bf(y[2]) | ((uint32_t)f2bf(y[3]) << 16);
        uint32_t w2 = f2bf(y[4]) | ((uint32_t)f2bf(y[5]) << 16);
        uint32_t w3 = f2bf(y[6]) | ((uint32_t)f2bf(y[7]) << 16);
        // packed: lane l holds k = l*8..l*8+7 of this row -> panel l
        ((uint4*)Yb)[(size_t)l * 16384 + row] = make_uint4(w0, w1, w2, w3);
    }
}

// ------------------------------------------------------------ launcher ----
extern "C" void kernel_launch(void* const* d_in, const int* in_sizes, int n_in,
                              void* d_out, int out_size, void* d_ws, size_t ws_size,
                              hipStream_t stream) {
    const float* verts = (const float*)d_in[0];
    const float* F = (const float*)d_in[1];
    const float* Wq = (const float*)d_in[2];
    const float* bq = (const float*)d_in[3];
    const float* Wk = (const float*)d_in[4];
    const float* bk = (const float*)d_in[5];
    const float* Wv = (const float*)d_in[6];
    const float* bv = (const float*)d_in[7];
    const float* Wo = (const float*)d_in[8];
    const float* bo = (const float*)d_in[9];
    const float* ln1g = (const float*)d_in[10];
    const float* ln1b = (const float*)d_in[11];
    const float* W1 = (const float*)d_in[12];
    const float* b1 = (const float*)d_in[13];
    const float* W2 = (const float*)d_in[14];
    const float* b2 = (const float*)d_in[15];
    const float* ln2g = (const float*)d_in[16];
    const float* ln2b = (const float*)d_in[17];
    float* out = (float*)d_out;

    char* ws = (char*)d_ws;
    // arena (lifetime-overlapped), ~177.5 MB:
    u16* QKV = (u16*)(ws);                         // [0, 96MB)  G1 -> attn (row-major)
    float* Q0 = (float*)(ws);                      // [0, 32MB)  G2 output -> LN1
    u16* Hb = (u16*)(ws);                          // [0, 64MB)  G3 -> G4 (packed)  (after LN1)
    u16* ATT = (u16*)(ws + 100663296);             // [96, 128MB) attn -> G2 (packed)
    u16* xb = ATT;                                 //   reuse: LN1 -> G3 (packed)
    float* P0 = (float*)(ws + 100663296);          //   reuse: G4 output -> LN2 (32MB)
    u16* Fb = (u16*)(ws + 134217728);              // [128, 144.8MB) prep -> G1 (packed)
    float* X32 = (float*)(ws + 134217728);         //   reuse: LN1 -> LN2 (33.5MB)
    char* wsw = ws + 167772160;
    u16* WqkvT = (u16*)(wsw);                      // 3,145,728 (packed)
    u16* WoT = (u16*)(wsw + 3145728);              // 1,048,576 (packed)
    u16* W1T = (u16*)(wsw + 4194304);              // 2,097,152 (packed)
    u16* W2T = (u16*)(wsw + 6291456);              // 2,097,152 (packed)
    float* bqkv = (float*)(wsw + 8388608);         // 16,384 (padded)
    int* nbr = (int*)(wsw + 8404992);              // 1,310,720

    // PREP (one dispatch): transposes+pack + F pack + bias + KNN
    prep_kernel<<<12300, 256, 0, stream>>>(verts, F, Wq, Wk, Wv, Wo, W1, W2,
                                           bq, bk, bv, WqkvT, WoT, W1T, W2T,
                                           bqkv, Fb, nbr);
    // G1: QKV = Fb @ Wqkv + bias -> bf16 row-major [16384, 3072]
    gemm_bt<0><<<dim3(24, 128, 1), 256, 0, stream>>>(Fb, WqkvT, bqkv, QKV, nullptr, nullptr,
                                                     16384, 3072, 512, 16384, 3072, 0);
    // sparse attention -> ATT packed [16384, 1024]
    attn_kernel<<<4096, 256, 0, stream>>>(QKV, nbr, ATT);
    // G2 (no split-K): Q0 = ATT @ Wo -> fp32 [16384, 512]
    gemm_bt<3><<<dim3(4, 128, 1), 256, 0, stream>>>(ATT, WoT, nullptr, nullptr, Q0, nullptr,
                                                    16384, 512, 1024, 16384, 512, 0);
    // LN1: LN(Q0+bo+F) -> X32 fp32 + xb packed bf16
    ln12p_kernel<1, 1><<<4096, 256, 0, stream>>>(Q0, nullptr, F, bo, ln1g, ln1b, X32, xb);
    // G3: Hb = relu(xb @ W1 + b1) -> packed bf16 [16384, 2048]
    gemm_bt<1><<<dim3(16, 128, 1), 256, 0, stream>>>(xb, W1T, b1, Hb, nullptr, nullptr,
                                                     16384, 2048, 512, 16384, 2048, 0);
    // G4 (no split-K): P0 = Hb @ W2 -> fp32 [16384, 512]
    gemm_bt<3><<<dim3(4, 128, 1), 256, 0, stream>>>(Hb, W2T, nullptr, nullptr, P0, nullptr,
                                                    16384, 512, 2048, 16384, 512, 0);
    // LN2: LN(P0+b2+X32) -> out
    ln12p_kernel<0, 1><<<4096, 256, 0, stream>>>(P0, nullptr, X32, b2, ln2g, ln2b, out, nullptr);
}

// Round 9
// 496.120 us; speedup vs baseline: 1.7600x; 1.0077x over previous
//
#include <hip/hip_runtime.h>
#include <stdint.h>

typedef uint16_t u16;
typedef __bf16 bf16x8 __attribute__((ext_vector_type(8)));
typedef float f32x4 __attribute__((ext_vector_type(4)));

#define DEV static __device__ __forceinline__

DEV float bfbits_lo(uint32_t w) { union { uint32_t i; float f; } v; v.i = w << 16; return v.f; }
DEV float bfbits_hi(uint32_t w) { union { uint32_t i; float f; } v; v.i = w & 0xffff0000u; return v.f; }
DEV u16 f2bf(float f) {
    union { float f; uint32_t i; } v; v.f = f;
    uint32_t x = v.i;
    uint32_t r = (x + 0x7fffu + ((x >> 16) & 1u)) >> 16;  // RNE
    return (u16)r;
}

// DPP cross-lane permute within each 16-lane row: returns permuted value.
// CTRL: 0x124=row_ror:4, 0x128=row_ror:8, 0xB1=quad_perm xor1, 0x4E=quad_perm xor2
template <int CTRL>
DEV float dpp_get(float x) {
    union { float f; int i; } a, r;
    a.f = x;
    r.i = __builtin_amdgcn_update_dpp(0, a.i, CTRL, 0xf, 0xf, false);
    return r.f;
}

// async global->LDS DMA, 16B per lane. LDS dest must be wave-uniform base +
// lane*16 (HW semantics); our staging slots (base + tid*16) satisfy this.
#define GLL16(g, l)                                                        \
    __builtin_amdgcn_global_load_lds(                                      \
        (const __attribute__((address_space(1))) uint32_t*)(g),            \
        (__attribute__((address_space(3))) uint32_t*)(l), 16, 0, 0)

// Packed operand layout ("panels"): element (row, k) of a [R x K] matrix
// lives at u16 index ((k>>3)*R + row)*8 + (k&7)  == uint4 slot (k>>3)*R + row.
// A wave staging 64 consecutive rows of one panel reads 1KB CONTIGUOUS.

// ------------------------------------------------------------- PREP ----
// blocks 0..4095: weight transpose+pack; 4096..8191: F pack; 8192..8203:
// bias concat; 8204..12299: KNN.
__global__ __launch_bounds__(256) void prep_kernel(
    const float* __restrict__ verts, const float* __restrict__ F,
    const float* __restrict__ Wq, const float* __restrict__ Wk,
    const float* __restrict__ Wv, const float* __restrict__ Wo,
    const float* __restrict__ W1, const float* __restrict__ W2,
    const float* __restrict__ bq, const float* __restrict__ bk,
    const float* __restrict__ bv,
    u16* __restrict__ WqkvT, u16* __restrict__ WoT,
    u16* __restrict__ W1T, u16* __restrict__ W2T,
    float* __restrict__ bqkv, u16* __restrict__ Fb, int* __restrict__ nbr) {
    int blk = blockIdx.x;
    int tid = threadIdx.x;
    if (blk < 4096) {
        // transpose W[K][Nsrc] -> packed BT panels [(k>>3)*NB + noff + n][k&7]
        const float* in; u16* outp; int K, Nsrc, NB, noff, t = blk;
        if (t < 512) { in = Wq; outp = WqkvT; K = 512; Nsrc = 1024; NB = 3072; noff = 0; }
        else if (t < 1024) { t -= 512; in = Wk; outp = WqkvT; K = 512; Nsrc = 1024; NB = 3072; noff = 1024; }
        else if (t < 1536) { t -= 1024; in = Wv; outp = WqkvT; K = 512; Nsrc = 1024; NB = 3072; noff = 2048; }
        else if (t < 2048) { t -= 1536; in = Wo; outp = WoT; K = 1024; Nsrc = 512; NB = 512; noff = 0; }
        else if (t < 3072) { t -= 2048; in = W1; outp = W1T; K = 512; Nsrc = 2048; NB = 2048; noff = 0; }
        else { t -= 3072; in = W2; outp = W2T; K = 2048; Nsrc = 512; NB = 512; noff = 0; }
        int tilesX = Nsrc >> 5;
        int bx = t % tilesX, by = t / tilesX;
        int x0 = bx * 32, y0 = by * 32;
        __shared__ float tile[32][33];
        int tx = tid & 31, ty = tid >> 5;  // 32 x 8
#pragma unroll
        for (int r = 0; r < 4; r++) {
            int y = y0 + ty + r * 8;       // k index
            tile[ty + r * 8][tx] = in[(size_t)y * Nsrc + x0 + tx];
        }
        __syncthreads();
#pragma unroll
        for (int r = 0; r < 4; r++) {
            int n = x0 + ty + r * 8;       // source col
            int k = y0 + tx;
            outp[(((size_t)(k >> 3) * NB + noff + n) << 3) + (k & 7)] = f2bf(tile[tx][ty + r * 8]);
        }
    } else if (blk < 8192) {
        // pack F[16384][512] -> Fb panels (reads contiguous, writes strided->L2)
        int gi = (blk - 4096) * 256 + tid;   // 16384*64 slots
        int row = gi >> 6, p = gi & 63;
        const float4* src = (const float4*)(F + (size_t)row * 512 + p * 8);
        float4 a = src[0], c = src[1];
        uint32_t w0 = f2bf(a.x) | ((uint32_t)f2bf(a.y) << 16);
        uint32_t w1 = f2bf(a.z) | ((uint32_t)f2bf(a.w) << 16);
        uint32_t w2 = f2bf(c.x) | ((uint32_t)f2bf(c.y) << 16);
        uint32_t w3 = f2bf(c.z) | ((uint32_t)f2bf(c.w) << 16);
        ((uint4*)Fb)[(size_t)p * 16384 + row] = make_uint4(w0, w1, w2, w3);
    } else if (blk < 8204) {
        int i = (blk - 8192) * 256 + tid;
        if (i < 1024) bqkv[i] = bq[i];
        else if (i < 2048) bqkv[i] = bk[i - 1024];
        else if (i < 3072) bqkv[i] = bv[i - 2048];
    } else {
        // ---- KNN top-20 (1 wave per query), packed-argmin (R3, verified) ----
        int wv = (blk - 8204) * 4 + (tid >> 6);
        int l = tid & 63;
        int b = wv >> 10, n = wv & 1023;
        const float* vb = verts + (size_t)b * 1024 * 3;
        float qx = vb[n * 3 + 0], qy = vb[n * 3 + 1], qz = vb[n * 3 + 2];
        float q2 = qx * qx + qy * qy + qz * qz;
        float pd[16];
#pragma unroll
        for (int t = 0; t < 16; t++) {
            int p = l + 64 * t;
            float px = vb[p * 3 + 0], py = vb[p * 3 + 1], pz = vb[p * 3 + 2];
            float p2 = px * px + py * py + pz * pz;
            float dot = qx * px + qy * py + qz * pz;
            float dv = q2 + p2 - 2.f * dot + 1.0f;
            uint32_t bits = (__float_as_uint(dv) & ~0xFu) | (uint32_t)t;
            pd[t] = __uint_as_float(bits);
        }
        int* outp = nbr + (size_t)wv * 20;
        for (int it = 0; it < 20; it++) {
            float m01 = fminf(pd[0], pd[1]),   m23 = fminf(pd[2], pd[3]);
            float m45 = fminf(pd[4], pd[5]),   m67 = fminf(pd[6], pd[7]);
            float m89 = fminf(pd[8], pd[9]),   mab = fminf(pd[10], pd[11]);
            float mcd = fminf(pd[12], pd[13]), mef = fminf(pd[14], pd[15]);
            float m = fminf(fminf(fminf(m01, m23), fminf(m45, m67)),
                            fminf(fminf(m89, mab), fminf(mcd, mef)));
            m = fminf(m, dpp_get<0x124>(m));
            m = fminf(m, dpp_get<0x128>(m));
            m = fminf(m, dpp_get<0xB1>(m));
            m = fminf(m, dpp_get<0x4E>(m));
            m = fminf(m, __shfl_xor(m, 16));
            m = fminf(m, __shfl_xor(m, 32));
            bool mine = false;
#pragma unroll
            for (int t = 0; t < 16; t++) mine |= (pd[t] == m);
            unsigned long long bal = __ballot(mine);
            int wl = (int)__builtin_ctzll(bal);
            if (l == wl) {
#pragma unroll
                for (int t = 0; t < 16; t++) if (pd[t] == m) pd[t] = 3.4e38f;
            }
            if (l == 0) outp[it] = ((int)(__float_as_uint(m) & 15u)) * 64 + wl;
        }
    }
}

// ---------------------------------------------------------------- GEMM ----
// C[M,N] = A[M,K] * B[K,N], both operands packed-panel. bf16 in, fp32 accum,
// MFMA 16x16x32, BK=32, 128x128 tile, global_load_lds DMA staging.
// R8 change: 3-buffer / 2-tiles-in-flight pipeline with counted vmcnt(8).
// Arithmetic: compute phase/SIMD = 4 waves x 16 MFMA x ~5cy = 320cy, but A
// streams from HBM (~900cy latency) -> 1-deep prefetch stalls ~600cy/tile at
// the vmcnt (matches MfmaUtil 24%). 2-deep gives each tile's loads 2 compute
// phases + barriers (~700+cy) to land. Buffer staged at iter k held tile k-1,
// whose reads finished at k-1's trailing barrier -> no race. Packed-panel
// LDS layout is bank-conflict-free (SQ_LDS_BANK_CONFLICT=0 measured).
// LDS 48KB -> 3 blocks/CU cap (measured occupancy is below this anyway).
// EPI: 0 bias->bf16 row-major | 1 bias+relu->PACKED bf16 | 3 plain->fp32
template <int EPI>
__global__ __launch_bounds__(256) void gemm_bt(const u16* __restrict__ A,
                                               const u16* __restrict__ BT,
                                               const float* __restrict__ bias,
                                               u16* __restrict__ Cb,
                                               float* __restrict__ Cf,
                                               float* __restrict__ Cf2,
                                               int M, int N, int Klen,
                                               int MA, int NB, int Koff) {
    __shared__ __align__(16) u16 AsBuf[3][4096];   // 8KB each: [kq][row][8]
    __shared__ __align__(16) u16 BsBuf[3][4096];
    int tid = threadIdx.x;
    int id = blockIdx.y * gridDim.x + blockIdx.x;
    int by = id % gridDim.y, bx = id / gridDim.y;
    int m0 = by * 128, n0 = bx * 128;
    int kz = blockIdx.z;
    const uint4* A4 = (const uint4*)A + (size_t)kz * (Koff >> 3) * MA;
    const uint4* B4 = (const uint4*)BT + (size_t)kz * (Koff >> 3) * NB;
    int w = tid >> 6, l = tid & 63;
    int wr = w >> 1, wc = w & 1, quad = l >> 4, ln = l & 15;
    // staging: slot i=tid -> (panel q=tid>>7, row tid&127); i=tid+256 -> q+2
    int qA = tid >> 7, rA = tid & 127;
    const uint4* pA0 = A4 + (size_t)qA * MA + m0 + rA;
    const uint4* pA1 = pA0 + 2 * (size_t)MA;
    const uint4* pB0 = B4 + (size_t)qA * NB + n0 + rA;
    const uint4* pB1 = pB0 + 2 * (size_t)NB;

    f32x4 acc[4][4];
#pragma unroll
    for (int i = 0; i < 4; i++)
#pragma unroll
        for (int j = 0; j < 4; j++) acc[i][j] = (f32x4){0.f, 0.f, 0.f, 0.f};

#define STAGE(As, Bs, ko) do { size_t kq = (size_t)((ko) >> 3);              \
        GLL16(pA0 + kq * MA, (char*)(As) + tid * 16);                        \
        GLL16(pA1 + kq * MA, (char*)(As) + (tid + 256) * 16);                \
        GLL16(pB0 + kq * NB, (char*)(Bs) + tid * 16);                        \
        GLL16(pB1 + kq * NB, (char*)(Bs) + (tid + 256) * 16); } while (0)
#define COMPUTE(Asb, Bsb) do {                                                            \
        const bf16x8* Av = (const bf16x8*)(Asb);                                          \
        const bf16x8* Bv = (const bf16x8*)(Bsb);                                          \
        bf16x8 af[4], bfr[4];                                                             \
        _Pragma("unroll")                                                                 \
        for (int i = 0; i < 4; i++) af[i] = Av[quad * 128 + wr * 64 + i * 16 + ln];       \
        _Pragma("unroll")                                                                 \
        for (int j = 0; j < 4; j++) bfr[j] = Bv[quad * 128 + wc * 64 + j * 16 + ln];      \
        _Pragma("unroll")                                                                 \
        for (int i = 0; i < 4; i++)                                                       \
            _Pragma("unroll")                                                             \
            for (int j = 0; j < 4; j++)                                                   \
                acc[i][j] = __builtin_amdgcn_mfma_f32_16x16x32_bf16(af[i], bfr[j], acc[i][j], 0, 0, 0); \
    } while (0)

    char* sA0 = (char*)AsBuf[0]; char* sA1 = (char*)AsBuf[1]; char* sA2 = (char*)AsBuf[2];
    char* sB0 = (char*)BsBuf[0]; char* sB1 = (char*)BsBuf[1]; char* sB2 = (char*)BsBuf[2];

    int nIter = Klen >> 5;   // >= 16 for all shapes used
    STAGE(sA0, sB0, 0);                       // tile 0: 4 loads in flight
    STAGE(sA1, sB1, 32);                      // tile 1: 8 in flight
    for (int kt = 0; kt < nIter; kt++) {
        if (kt + 2 < nIter) {
            STAGE(sA2, sB2, (kt + 2) * 32);   // 12 in flight
            asm volatile("s_waitcnt vmcnt(8)" ::: "memory");   // tile kt landed
        } else if (kt + 1 < nIter) {
            asm volatile("s_waitcnt vmcnt(4)" ::: "memory");   // tile kt landed
        } else {
            asm volatile("s_waitcnt vmcnt(0)" ::: "memory");   // last tile landed
        }
        __builtin_amdgcn_s_barrier();
        COMPUTE(sA0, sB0);                    // tile kt
        __builtin_amdgcn_s_barrier();         // reads of buf0 done (safe to re-stage)
        char* t;
        t = sA0; sA0 = sA1; sA1 = sA2; sA2 = t;
        t = sB0; sB0 = sB1; sB1 = sB2; sB2 = t;
    }
#undef STAGE
#undef COMPUTE

    float* Cfz = (EPI == 3) ? (kz ? Cf2 : Cf) : Cf;
    // epilogue: row = m0+wr*64+i*16+quad*4+r, col = n0+wc*64+j*16+ln
#pragma unroll
    for (int i = 0; i < 4; i++) {
        int row_base = m0 + wr * 64 + i * 16 + quad * 4;
#pragma unroll
        for (int j = 0; j < 4; j++) {
            int col = n0 + wc * 64 + j * 16 + ln;
            float bb = (EPI == 3) ? 0.f : bias[col];
#pragma unroll
            for (int r = 0; r < 4; r++) {
                int row = row_base + r;
                float v = acc[i][j][r] + bb;
                if (EPI == 0) Cb[(size_t)row * N + col] = f2bf(v);
                else if (EPI == 1)  // packed output (next GEMM's A operand)
                    Cb[(((size_t)(col >> 3) * M + row) << 3) + (col & 7)] = f2bf(v > 0.f ? v : 0.f);
                else Cfz[(size_t)row * N + col] = v;
            }
        }
    }
}

// ----------------------------------------------------- sparse attention ----
// EXACT proven version (89.4us, 92 VGPR, absmax 0.03125). Two phases,
// __shfl_xor 16-lane reduce in phase 1 (its lgkmcnt waits act as scheduling
// fences that stop the compiler from hoisting 20 iterations' loads -> keeps
// register pressure low). THREE failed perturbations (R1 fuse: 152 VGPR;
// R2 DPP+exp-in-loop: 196 VGPR; R6 launch_bounds(256,8): 32 VGPR + 713MB
// scratch spill, 400us). DO NOT TOUCH. XCD swizzle proven (FETCH 305->111MB).
__global__ __launch_bounds__(256) void attn_kernel(const u16* __restrict__ QKV,
                                                   const int* __restrict__ nbr,
                                                   u16* __restrict__ outA) {
    int tid = threadIdx.x;
    int bid = blockIdx.x;
    int swz = (bid & 7) * 512 + (bid >> 3);   // 4096 blocks, bijective
    int wv = swz * 4 + (tid >> 6);  // b*1024+n
    int l = tid & 63;
    int h = l >> 4, sx = l & 15;
    int bbase = (wv >> 10) << 10;

    int nv = 0;
    if (l < 20) nv = nbr[(size_t)wv * 20 + l];

    const uint32_t* qp = (const uint32_t*)(QKV + (size_t)wv * 3072 + h * 256 + sx * 16);
    uint32_t qw[8];
    *(uint4*)(qw) = *(const uint4*)qp;
    *(uint4*)(qw + 4) = *(const uint4*)(qp + 4);
    float qf[16];
#pragma unroll
    for (int i = 0; i < 8; i++) { qf[2 * i] = bfbits_lo(qw[i]); qf[2 * i + 1] = bfbits_hi(qw[i]); }

    float wj[20];
#pragma unroll
    for (int j = 0; j < 20; j++) {
        int m = __shfl(nv, j);
        const uint32_t* kp = (const uint32_t*)(QKV + (size_t)(bbase + m) * 3072 + 1024 + h * 256 + sx * 16);
        uint32_t kw[8];
        *(uint4*)(kw) = *(const uint4*)kp;
        *(uint4*)(kw + 4) = *(const uint4*)(kp + 4);
        float acc = 0.f;
#pragma unroll
        for (int i = 0; i < 8; i++) {
            acc += qf[2 * i] * bfbits_lo(kw[i]);
            acc += qf[2 * i + 1] * bfbits_hi(kw[i]);
        }
#pragma unroll
        for (int off = 1; off < 16; off <<= 1) acc += __shfl_xor(acc, off);
        wj[j] = acc * 0.0625f;
    }
    float ssum = 0.f;
#pragma unroll
    for (int j = 0; j < 20; j++) { wj[j] = __expf(wj[j]); ssum += wj[j]; }
    float inv = 1.f / ssum;

    float o[16];
#pragma unroll
    for (int i = 0; i < 16; i++) o[i] = 0.f;
#pragma unroll
    for (int j = 0; j < 20; j++) {
        int m = __shfl(nv, j);
        const uint32_t* vp = (const uint32_t*)(QKV + (size_t)(bbase + m) * 3072 + 2048 + h * 256 + sx * 16);
        uint32_t vw[8];
        *(uint4*)(vw) = *(const uint4*)vp;
        *(uint4*)(vw + 4) = *(const uint4*)(vp + 4);
        float ww = wj[j] * inv;
#pragma unroll
        for (int i = 0; i < 8; i++) {
            o[2 * i] += ww * bfbits_lo(vw[i]);
            o[2 * i + 1] += ww * bfbits_hi(vw[i]);
        }
    }
    uint32_t ow[8];
#pragma unroll
    for (int i = 0; i < 8; i++) ow[i] = f2bf(o[2 * i]) | ((uint32_t)f2bf(o[2 * i + 1]) << 16);
    // packed store: cols h*256+sx*16 .. +15 -> panels h*32+sx*2, h*32+sx*2+1, row wv
    size_t slot = (size_t)(h * 32 + sx * 2) * 16384 + wv;
    ((uint4*)outA)[slot] = make_uint4(ow[0], ow[1], ow[2], ow[3]);
    ((uint4*)outA)[slot + 16384] = make_uint4(ow[4], ow[5], ow[6], ow[7]);
}

// ------------------------------------------------- LN over GEMM output ----
// LN((NP==2 ? P0+P1 : P0) + res + biasv) -> Yf fp32 (+ Yb PACKED bf16 if WB)
template <int WB, int NP>
__global__ __launch_bounds__(256) void ln12p_kernel(const float* __restrict__ P0,
                                                    const float* __restrict__ P1,
                                                    const float* __restrict__ res,
                                                    const float* __restrict__ biasv,
                                                    const float* __restrict__ g,
                                                    const float* __restrict__ bparm,
                                                    float* __restrict__ Yf,
                                                    u16* __restrict__ Yb) {
    int tid = threadIdx.x;
    int row = blockIdx.x * 4 + (tid >> 6);
    int l = tid & 63;
    size_t base = (size_t)row * 512;
    const float4* p0 = (const float4*)(P0 + base) + l * 2;
    const float4* rr = (const float4*)(res + base) + l * 2;
    const float4* bv = (const float4*)biasv + l * 2;
    float xs[8];
#pragma unroll
    for (int h = 0; h < 2; h++) {
        float4 a = p0[h], c = rr[h], d = bv[h];
        xs[4 * h + 0] = a.x + c.x + d.x;
        xs[4 * h + 1] = a.y + c.y + d.y;
        xs[4 * h + 2] = a.z + c.z + d.z;
        xs[4 * h + 3] = a.w + c.w + d.w;
        if constexpr (NP == 2) {
            const float4* p1 = (const float4*)(P1 + base) + l * 2;
            float4 b = p1[h];
            xs[4 * h + 0] += b.x; xs[4 * h + 1] += b.y;
            xs[4 * h + 2] += b.z; xs[4 * h + 3] += b.w;
        }
    }
    float s = 0.f;
#pragma unroll
    for (int i = 0; i < 8; i++) s += xs[i];
#pragma unroll
    for (int off = 32; off >= 1; off >>= 1) s += __shfl_xor(s, off);
    float mu = s * (1.f / 512.f);
    float q = 0.f;
#pragma unroll
    for (int i = 0; i < 8; i++) { float dd = xs[i] - mu; q += dd * dd; }
#pragma unroll
    for (int off = 32; off >= 1; off >>= 1) q += __shfl_xor(q, off);
    float var = q * (1.f / 512.f);
    float rs = rsqrtf(var + 1e-5f);
    const float4* gp = (const float4*)g + l * 2;
    const float4* bp = (const float4*)bparm + l * 2;
    float4 g0 = gp[0], g1 = gp[1], b0 = bp[0], b1 = bp[1];
    float gg[8] = {g0.x, g0.y, g0.z, g0.w, g1.x, g1.y, g1.z, g1.w};
    float bbv[8] = {b0.x, b0.y, b0.z, b0.w, b1.x, b1.y, b1.z, b1.w};
    float y[8];
#pragma unroll
    for (int i = 0; i < 8; i++) y[i] = (xs[i] - mu) * rs * gg[i] + bbv[i];
    float4* yo = (float4*)(Yf + base) + l * 2;
    yo[0] = make_float4(y[0], y[1], y[2], y[3]);
    yo[1] = make_float4(y[4], y[5], y[6], y[7]);
    if (WB) {
        uint32_t w0 = f2bf(y[0]) | ((uint32_t)f2bf(y[1]) << 16);
        uint32_t w1 = f2bf(y[2]) | ((uint32_t)f2bf(y[3]) << 16);
        uint32_t w2 = f2bf(y[4]) | ((uint32_t)f2bf(y[5]) << 16);
        uint32_t w3 = f2bf(y[6]) | ((uint32_t)f2bf(y[7]) << 16);
        // packed: lane l holds k = l*8..l*8+7 of this row -> panel l
        ((uint4*)Yb)[(size_t)l * 16384 + row] = make_uint4(w0, w1, w2, w3);
    }
}

// ------------------------------------------------------------ launcher ----
extern "C" void kernel_launch(void* const* d_in, const int* in_sizes, int n_in,
                              void* d_out, int out_size, void* d_ws, size_t ws_size,
                              hipStream_t stream) {
    const float* verts = (const float*)d_in[0];
    const float* F = (const float*)d_in[1];
    const float* Wq = (const float*)d_in[2];
    const float* bq = (const float*)d_in[3];
    const float* Wk = (const float*)d_in[4];
    const float* bk = (const float*)d_in[5];
    const float* Wv = (const float*)d_in[6];
    const float* bv = (const float*)d_in[7];
    const float* Wo = (const float*)d_in[8];
    const float* bo = (const float*)d_in[9];
    const float* ln1g = (const float*)d_in[10];
    const float* ln1b = (const float*)d_in[11];
    const float* W1 = (const float*)d_in[12];
    const float* b1 = (const float*)d_in[13];
    const float* W2 = (const float*)d_in[14];
    const float* b2 = (const float*)d_in[15];
    const float* ln2g = (const float*)d_in[16];
    const float* ln2b = (const float*)d_in[17];
    float* out = (float*)d_out;

    char* ws = (char*)d_ws;
    // arena (lifetime-overlapped), ~177.5 MB:
    u16* QKV = (u16*)(ws);                         // [0, 96MB)  G1 -> attn (row-major)
    float* Q0 = (float*)(ws);                      // [0, 32MB)  G2 output -> LN1
    u16* Hb = (u16*)(ws);                          // [0, 64MB)  G3 -> G4 (packed)  (after LN1)
    u16* ATT = (u16*)(ws + 100663296);             // [96, 128MB) attn -> G2 (packed)
    u16* xb = ATT;                                 //   reuse: LN1 -> G3 (packed)
    float* P0 = (float*)(ws + 100663296);          //   reuse: G4 output -> LN2 (32MB)
    u16* Fb = (u16*)(ws + 134217728);              // [128, 144.8MB) prep -> G1 (packed)
    float* X32 = (float*)(ws + 134217728);         //   reuse: LN1 -> LN2 (33.5MB)
    char* wsw = ws + 167772160;
    u16* WqkvT = (u16*)(wsw);                      // 3,145,728 (packed)
    u16* WoT = (u16*)(wsw + 3145728);              // 1,048,576 (packed)
    u16* W1T = (u16*)(wsw + 4194304);              // 2,097,152 (packed)
    u16* W2T = (u16*)(wsw + 6291456);              // 2,097,152 (packed)
    float* bqkv = (float*)(wsw + 8388608);         // 16,384 (padded)
    int* nbr = (int*)(wsw + 8404992);              // 1,310,720

    // PREP (one dispatch): transposes+pack + F pack + bias + KNN
    prep_kernel<<<12300, 256, 0, stream>>>(verts, F, Wq, Wk, Wv, Wo, W1, W2,
                                           bq, bk, bv, WqkvT, WoT, W1T, W2T,
                                           bqkv, Fb, nbr);
    // G1: QKV = Fb @ Wqkv + bias -> bf16 row-major [16384, 3072]
    gemm_bt<0><<<dim3(24, 128, 1), 256, 0, stream>>>(Fb, WqkvT, bqkv, QKV, nullptr, nullptr,
                                                     16384, 3072, 512, 16384, 3072, 0);
    // sparse attention -> ATT packed [16384, 1024]
    attn_kernel<<<4096, 256, 0, stream>>>(QKV, nbr, ATT);
    // G2 (no split-K): Q0 = ATT @ Wo -> fp32 [16384, 512]
    gemm_bt<3><<<dim3(4, 128, 1), 256, 0, stream>>>(ATT, WoT, nullptr, nullptr, Q0, nullptr,
                                                    16384, 512, 1024, 16384, 512, 0);
    // LN1: LN(Q0+bo+F) -> X32 fp32 + xb packed bf16
    ln12p_kernel<1, 1><<<4096, 256, 0, stream>>>(Q0, nullptr, F, bo, ln1g, ln1b, X32, xb);
    // G3: Hb = relu(xb @ W1 + b1) -> packed bf16 [16384, 2048]
    gemm_bt<1><<<dim3(16, 128, 1), 256, 0, stream>>>(xb, W1T, b1, Hb, nullptr, nullptr,
                                                     16384, 2048, 512, 16384, 2048, 0);
    // G4 (no split-K): P0 = Hb @ W2 -> fp32 [16384, 512]
    gemm_bt<3><<<dim3(4, 128, 1), 256, 0, stream>>>(Hb, W2T, nullptr, nullptr, P0, nullptr,
                                                    16384, 512, 2048, 16384, 512, 0);
    // LN2: LN(P0+b2+X32) -> out
    ln12p_kernel<0, 1><<<4096, 256, 0, stream>>>(P0, nullptr, X32, b2, ln2g, ln2b, out, nullptr);
}